// Round 4
// baseline (8987.781 us; speedup 1.0000x reference)
//
#include <hip/hip_runtime.h>
#include <math.h>

constexpr float CC   = 1.2f;
constexpr float SQC  = 1.09544511501033215f;      // sqrt(1.2)
constexpr float MAXN = (1.0f - 4e-3f) / SQC;      // geoopt projx maxnorm
constexpr float MINN = 1e-15f;

// ---------------- fast per-lane scalar math ----------------
__device__ __forceinline__ float art_(float x){
  x = fminf(fmaxf(x, -0.9999999f), 0.9999999f);
  return 0.5f * __logf((1.0f + x) / (1.0f - x));
}
__device__ __forceinline__ float tanh_(float x){
  x = fminf(fmaxf(x, -15.0f), 15.0f);
  float e = __expf(2.0f * x);
  return (e - 1.0f) / (e + 1.0f);
}
__device__ __forceinline__ float wsum(float v){
#pragma unroll
  for(int i=32;i>0;i>>=1) v += __shfl_xor(v, i, 64);
  return v;
}

struct HS { float ca, cb, nv; };
__device__ __forceinline__ HS hyper_chain(float m2, float meb, float xn_in, float y2){
  float xn  = fmaxf(xn_in, MINN);
  float mxn = fmaxf(sqrtf(m2), MINN);
  float r   = art_(SQC*xn);
  float s   = tanh_(mxn/xn*r)/(mxn*SQC);
  float nr  = s*mxn;
  if(nr > MAXN){ s *= MAXN/nr; nr = MAXN; }
  float xy = s*meb, x2 = nr*nr;
  float den = fmaxf(1.f + 2.f*CC*xy + CC*CC*x2*y2, MINN);
  float A   = (1.f + 2.f*CC*xy + CC*y2)/den;
  float Bc  = (1.f - CC*x2)/den;
  float n3  = sqrtf(fmaxf(A*A*x2 + 2.f*A*Bc*xy + Bc*Bc*y2, 0.f));
  float rho = (n3 > MAXN) ? MAXN/n3 : 1.f;
  HS h; h.nv = fminf(n3, MAXN); h.ca = rho*A*s; h.cb = rho*Bc;
  return h;
}

// ---------------- setup kernel ----------------
// ws: [0..127] u1=Wae^T Wte | [128..255] u2=Wae^T Wth | [256..335] eb1(80)
// [336..447] eb2 padded 112 (zeros 104..111) | [448..575] eb3(128)
// [576..703] eba(128) | [704] c1 [705] c2 [706..709] y2h1,y2h2,y2h3,y2ah
// [710] EBW1 [711] EBW2 | [712..823] be2 padded 112 | park at ws+1024
__global__ void k_setup(const float* __restrict__ Wae, const float* __restrict__ bae,
                        const float* __restrict__ bh1, const float* __restrict__ bh2,
                        const float* __restrict__ bh3, const float* __restrict__ bah,
                        const float* __restrict__ Wte, const float* __restrict__ Wth,
                        const float* __restrict__ be2, float* __restrict__ ws){
  const int tid = threadIdx.x;            // 256 threads, 1 block
  {
    const int which = tid >> 7, k = tid & 127;
    const float* wv = which ? Wth : Wte;
    float s = 0.f;
#pragma unroll 4
    for(int j=0;j<128;++j) s += Wae[j*128+k] * wv[j];
    ws[which*128 + k] = s;
  }
  if(tid >= 128 && tid < 240){
    const int j = tid - 128;
    ws[712+j] = (j < 104) ? be2[j] : 0.f;
  }
  if(tid < 64){
    const int l = tid;
    float p1=0.f, p2=0.f;
    for(int j=l;j<128;j+=64){ p1 += bae[j]*Wte[j]; p2 += bae[j]*Wth[j]; }
    p1 = wsum(p1); p2 = wsum(p2);
    if(l==0){ ws[704]=p1; ws[705]=p2; }
    if(l<8) ws[336+104+l] = 0.f;    // eb2 pad zeros
    const float* bs[4] = {bh1,bh2,bh3,bah};
    const int dims[4]  = {80,104,128,128};
    const int offs[4]  = {256,336,448,576};
    for(int v=0;v<4;++v){
      const float* bp = bs[v]; const int D = dims[v];
      float q = 0.f;
      for(int j=l;j<D;j+=64) q += bp[j]*bp[j];
      q = wsum(q);
      float nb = fmaxf(sqrtf(q), MINN);
      float th = tanhf(fminf(fmaxf(SQC*nb,-15.f),15.f));
      float coef = th/(SQC*nb);
      float ne = th/SQC;
      if(ne > MAXN){ coef *= MAXN/ne; ne = MAXN; }
      for(int j=l;j<D;j+=64) ws[offs[v]+j] = coef*bp[j];
      if(l==0) ws[706+v] = ne*ne;
      if(v==3){
        float e1=0.f, e2=0.f;
        for(int j=l;j<D;j+=64){ e1 += bp[j]*Wte[j]; e2 += bp[j]*Wth[j]; }
        e1 = wsum(e1)*coef; e2 = wsum(e2)*coef;
        if(l==0){ ws[710]=e1; ws[711]=e2; }
      }
    }
  }
}

// ---------------- per-wave weight streaming (quarter rows) ----------------
// Rows padded to KP in LDS ring (per-wave 1024 floats = 2 chunks of 512).
// Guarded loads: f < fmax (float index in KP-padded space).
template<int K,int KP>
__device__ __forceinline__ float4 ld1(const float* __restrict__ W, int f, int fmax){
  if(f >= fmax) return make_float4(0.f,0.f,0.f,0.f);
  if constexpr (K == KP){
    return *(const float4*)(W + f);
  } else {
    const int row = f >> 7, col = f & 127;   // KP==128 here
    if(col >= K) return make_float4(0.f,0.f,0.f,0.f);
    return *(const float4*)(W + row*K + col);
  }
}

template<int K,int KP,int CNT,typename F>
__device__ __forceinline__ void stream_q(const float* __restrict__ Wq,
                                         float* __restrict__ ring, int t,
                                         int fmax, const float (&xin)[K], F&& sink){
  constexpr int FT  = CNT*KP;
  constexpr int NCH = (FT + 511) >> 9;
  constexpr int NG  = CNT >> 2;
  const int l4 = t << 2;
  float4 q0 = make_float4(0.f,0.f,0.f,0.f), q1 = q0;
  {
    float4 p0 = ld1<K,KP>(Wq, l4, fmax);
    float4 p1 = ld1<K,KP>(Wq, l4+256, fmax);
    if(NCH > 1){
      q0 = ld1<K,KP>(Wq, 512+l4, fmax);
      q1 = ld1<K,KP>(Wq, 512+l4+256, fmax);
    }
    *(float4*)(ring + l4) = p0;
    *(float4*)(ring + 256 + l4) = p1;
  }
  int cm = 0, nl = 2;
#pragma unroll
  for(int g=0; g<NG; ++g){
    const int need = ((g+1)*4*KP - 1) >> 9;
    if(cm < need){
      ++cm;
      float* dst = ring + ((cm & 1) << 9);
      *(float4*)(dst + l4) = q0;
      *(float4*)(dst + 256 + l4) = q1;
      if(nl < NCH){
        q0 = ld1<K,KP>(Wq, (nl<<9)+l4, fmax);
        q1 = ld1<K,KP>(Wq, (nl<<9)+l4+256, fmax);
      }
      ++nl;
    }
    const float* rg = ring + ((g*4*KP) & 1023);
    float a0=0.f,a1=0.f,a2=0.f,a3=0.f;
#pragma unroll
    for(int k=0;k<K;k+=4){
      float4 w0 = *(const float4*)(rg + 0*KP + k);
      float4 w1 = *(const float4*)(rg + 1*KP + k);
      float4 w2 = *(const float4*)(rg + 2*KP + k);
      float4 w3 = *(const float4*)(rg + 3*KP + k);
      const float xa=xin[k], xb=xin[k+1], xc=xin[k+2], xd=xin[k+3];
      a0 = fmaf(w0.w,xd, fmaf(w0.z,xc, fmaf(w0.y,xb, fmaf(w0.x,xa, a0))));
      a1 = fmaf(w1.w,xd, fmaf(w1.z,xc, fmaf(w1.y,xb, fmaf(w1.x,xa, a1))));
      a2 = fmaf(w2.w,xd, fmaf(w2.z,xc, fmaf(w2.y,xb, fmaf(w2.x,xa, a2))));
      a3 = fmaf(w3.w,xd, fmaf(w3.z,xc, fmaf(w3.y,xb, fmaf(w3.x,xa, a3))));
    }
    sink(g<<2, a0, a1, a2, a3);
  }
}

// partial exchange across 4 waves (slot-rotated; single barrier)
template<int N>
__device__ __forceinline__ void exch(float* __restrict__ pex, int w, int t,
                                     int slot, float* v){
#pragma unroll
  for(int i=0;i<N;++i) pex[(slot+i)*256 + (w<<6) + t] = v[i];
  __syncthreads();
#pragma unroll
  for(int i=0;i<N;++i){
    const float* p = pex + (slot+i)*256 + t;
    v[i] = (p[0] + p[64]) + (p[128] + p[192]);
  }
}

// ---------------- LDS layout (floats) ----------------
constexpr int L_ACT  = 0;       // 64 tokens x 132 (token-major activations)
constexpr int L_RING = 8448;    // 4 waves x 1024
constexpr int L_PEX  = 12544;   // 4 slots x 256
constexpr int L_WG   = 13568;   // wge 64 | g2 64
constexpr int L_PV   = 13696;   // 512 pooling partials
constexpr int L_OV   = 14208;   // 256
constexpr int L_TOT  = 14464;   // 57,856 B -> 2 blocks/CU (8 waves/CU)

// ---------------- main kernel: 1 block (4 waves) per batch row ----------------
// lane t = token; wave w owns a quarter of each layer's output rows.
template<bool WSPARK>
__global__ __launch_bounds__(256, 2) void k_main(
    const float* __restrict__ x,
    const float* __restrict__ We1, const float* __restrict__ be1,
    const float* __restrict__ We2,
    const float* __restrict__ We3, const float* __restrict__ be3,
    const float* __restrict__ Wh1, const float* __restrict__ Wh2,
    const float* __restrict__ Wh3, const float* __restrict__ Wah,
    const float* __restrict__ Wte, const float* __restrict__ bte,
    const float* __restrict__ Wth, const float* __restrict__ bth,
    const float* __restrict__ Wf1, const float* __restrict__ bf1,
    const float* __restrict__ Wf2, const float* __restrict__ bf2,
    const float* __restrict__ ws, float* __restrict__ park,
    float* __restrict__ out){
  extern __shared__ float lds[];
  float* ACT  = lds + L_ACT;
  float* PEX  = lds + L_PEX;
  float* WG   = lds + L_WG;
  float* PV   = lds + L_PV;
  float* OV   = lds + L_OV;
  float* lpark= lds + L_TOT;
  const int tid = threadIdx.x, t = tid & 63, w = tid >> 6, b = blockIdx.x;
  float* ring = lds + L_RING + (w << 10);
  constexpr int PSTR = WSPARK ? 128 : 132;

  const float* u1  = ws;
  const float* u2  = ws + 128;
  const float* eb1 = ws + 256;
  const float* eb2 = ws + 336;   // padded 112
  const float* eb3 = ws + 448;
  const float* eba = ws + 576;
  const float* be2 = ws + 712;   // padded 112

  const int s80  = 20*w;         // OUT=80 quarters
  const int s104 = 28*w;         // OUT=104 padded to 112
  const int s128 = 32*w;         // OUT=128 quarters

  float poe = 0.f, poh = 0.f;
  const int pj = tid & 127, phalf = tid >> 7;   // pooling role

  for(int tile=0; tile<2; ++tile){
    const int s0 = tile*64;
    float* pk = WSPARK ? (park + (((size_t)(b*2+tile))<<13)) : lpark;

    // ---- x0 + expmap0 scalars (all waves redundant) ----
    float x0[32];
#pragma unroll
    for(int c=0;c<32;++c) x0[c] = x[((size_t)b*32 + c)*128 + s0 + t];
    float n2 = 0.f;
#pragma unroll
    for(int c=0;c<32;++c) n2 = fmaf(x0[c],x0[c],n2);
    float n0  = fmaxf(sqrtf(n2), MINN);
    float th0 = tanh_(SQC*n0);
    float nh  = th0/SQC;
    float scl = th0/(SQC*n0);
    if(nh > MAXN){ scl *= MAXN/nh; nh = MAXN; }

    // ---- H1: 32->80, mob_relu ----
    float nf1;
    {
      float r[20]; float pp[2] = {0.f,0.f};
      stream_q<32,32,20>(Wh1 + s80*32, ring, t, 640, x0,
        [&](int i,float a0,float a1,float a2,float a3){
          r[i]=a0; r[i+1]=a1; r[i+2]=a2; r[i+3]=a3;
          pp[0] = fmaf(a3,a3, fmaf(a2,a2, fmaf(a1,a1, fmaf(a0,a0, pp[0]))));
          const float* e = eb1 + s80 + i;
          pp[1] = fmaf(a3,e[3], fmaf(a2,e[2], fmaf(a1,e[1], fmaf(a0,e[0], pp[1]))));
        });
      exch<2>(PEX,w,t,0,pp);
      float m2 = pp[0]*scl*scl, meb = pp[1]*scl;
      HS h = hyper_chain(m2, meb, nh, ws[706]);
      float nvc = fmaxf(h.nv, MINN);
      float lam = art_(SQC*nvc)/(SQC*nvc);
      float ca = h.ca*scl, cb = h.cb;
      float prn[1] = {0.f};
#pragma unroll
      for(int i=0;i<20;++i){
        float v = fmaf(ca, r[i], cb*eb1[s80+i]);
        r[i] = fmaxf(lam*v, 0.f);
        prn[0] = fmaf(r[i], r[i], prn[0]);
      }
      exch<1>(PEX,w,t,2,prn);
      float rn = fmaxf(sqrtf(prn[0]), MINN);
      float th = tanh_(SQC*rn);
      float tau = th/(SQC*rn); nf1 = th/SQC;
      if(nf1 > MAXN){ tau *= MAXN/nf1; nf1 = MAXN; }
#pragma unroll
      for(int i=0;i<20;i+=4)
        *(float4*)(ACT + t*132 + s80 + i) =
          make_float4(tau*r[i],tau*r[i+1],tau*r[i+2],tau*r[i+3]);
      __syncthreads();
    }

    // ---- H2: 80->104(pad112), mob_relu ----
    float nf2;
    {
      float xin[80];
#pragma unroll
      for(int k=0;k<80;k+=4){
        float4 v = *(const float4*)(ACT + t*132 + k);
        xin[k]=v.x; xin[k+1]=v.y; xin[k+2]=v.z; xin[k+3]=v.w;
      }
      float r[28]; float pp[2] = {0.f,0.f};
      stream_q<80,128,28>(Wh2 + s104*80, ring, t, (104-s104)*128, xin,
        [&](int i,float a0,float a1,float a2,float a3){
          r[i]=a0; r[i+1]=a1; r[i+2]=a2; r[i+3]=a3;
          pp[0] = fmaf(a3,a3, fmaf(a2,a2, fmaf(a1,a1, fmaf(a0,a0, pp[0]))));
          const float* e = eb2 + s104 + i;
          pp[1] = fmaf(a3,e[3], fmaf(a2,e[2], fmaf(a1,e[1], fmaf(a0,e[0], pp[1]))));
        });
      exch<2>(PEX,w,t,0,pp);
      HS h = hyper_chain(pp[0], pp[1], nf1, ws[707]);
      float nvc = fmaxf(h.nv, MINN);
      float lam = art_(SQC*nvc)/(SQC*nvc);
      float prn[1] = {0.f};
#pragma unroll
      for(int i=0;i<28;++i){
        float v = fmaf(h.ca, r[i], h.cb*eb2[s104+i]);
        r[i] = fmaxf(lam*v, 0.f);
        prn[0] = fmaf(r[i], r[i], prn[0]);
      }
      exch<1>(PEX,w,t,2,prn);
      float rn = fmaxf(sqrtf(prn[0]), MINN);
      float th = tanh_(SQC*rn);
      float tau = th/(SQC*rn); nf2 = th/SQC;
      if(nf2 > MAXN){ tau *= MAXN/nf2; nf2 = MAXN; }
#pragma unroll
      for(int i=0;i<28;i+=4)
        *(float4*)(ACT + t*132 + s104 + i) =
          make_float4(tau*r[i],tau*r[i+1],tau*r[i+2],tau*r[i+3]);
      __syncthreads();
    }

    // ---- H3: 104->128 (no relu) -> out_h (ACT + park); Wah scalar pass ----
    float xnh, rr, th_wte, th_wth;
    {
      float xin[104];
#pragma unroll
      for(int k=0;k<104;k+=4){
        float4 v = *(const float4*)(ACT + t*132 + k);
        xin[k]=v.x; xin[k+1]=v.y; xin[k+2]=v.z; xin[k+3]=v.w;
      }
      float r[32]; float pp[2] = {0.f,0.f};
      stream_q<104,128,32>(Wh3 + s128*104, ring, t, 4096, xin,
        [&](int i,float a0,float a1,float a2,float a3){
          r[i]=a0; r[i+1]=a1; r[i+2]=a2; r[i+3]=a3;
          pp[0] = fmaf(a3,a3, fmaf(a2,a2, fmaf(a1,a1, fmaf(a0,a0, pp[0]))));
          const float* e = eb3 + s128 + i;
          pp[1] = fmaf(a3,e[3], fmaf(a2,e[2], fmaf(a1,e[1], fmaf(a0,e[0], pp[1]))));
        });
      exch<2>(PEX,w,t,0,pp);
      HS h = hyper_chain(pp[0], pp[1], nf2, ws[708]);
      xnh = fmaxf(h.nv, MINN);
      rr  = art_(SQC*xnh);
#pragma unroll
      for(int i=0;i<32;i+=4){
        float v0 = fmaf(h.ca, r[i  ], h.cb*eb3[s128+i  ]);
        float v1 = fmaf(h.ca, r[i+1], h.cb*eb3[s128+i+1]);
        float v2 = fmaf(h.ca, r[i+2], h.cb*eb3[s128+i+2]);
        float v3 = fmaf(h.ca, r[i+3], h.cb*eb3[s128+i+3]);
        float4 v4 = make_float4(v0,v1,v2,v3);
        *(float4*)(ACT + t*132 + s128 + i) = v4;
        *(float4*)(pk + t*PSTR + s128 + i) = v4;
      }
      __syncthreads();   // oh ready in ACT

      float oh[128];
#pragma unroll
      for(int k=0;k<128;k+=4){
        float4 v = *(const float4*)(ACT + t*132 + k);
        oh[k]=v.x; oh[k+1]=v.y; oh[k+2]=v.z; oh[k+3]=v.w;
      }
      float pq[4] = {0.f,0.f,0.f,0.f};
      stream_q<128,128,32>(Wah + s128*128, ring, t, 4096, oh,
        [&](int i,float a0,float a1,float a2,float a3){
          pq[0] = fmaf(a3,a3, fmaf(a2,a2, fmaf(a1,a1, fmaf(a0,a0, pq[0]))));
          const float* W1 = Wte + s128 + i;
          const float* W2 = Wth + s128 + i;
          const float* E  = eba + s128 + i;
          pq[1] = fmaf(a3,W1[3], fmaf(a2,W1[2], fmaf(a1,W1[1], fmaf(a0,W1[0], pq[1]))));
          pq[2] = fmaf(a3,W2[3], fmaf(a2,W2[2], fmaf(a1,W2[1], fmaf(a0,W2[0], pq[2]))));
          pq[3] = fmaf(a3,E[3],  fmaf(a2,E[2],  fmaf(a1,E[1],  fmaf(a0,E[0],  pq[3]))));
        });
      exch<4>(PEX,w,t,0,pq);
      float mxn = fmaxf(sqrtf(pq[0]), MINN);
      float s   = tanh_(mxn/xnh*rr)/(mxn*SQC);
      float nr  = s*mxn;
      if(nr > MAXN){ s *= MAXN/nr; nr = MAXN; }
      float xy = s*pq[3], x2 = nr*nr, y2 = ws[709];
      float den = fmaxf(1.f + 2.f*CC*xy + CC*CC*x2*y2, MINN);
      float A   = (1.f + 2.f*CC*xy + CC*y2)/den;
      float Bc  = (1.f - CC*x2)/den;
      float n3  = sqrtf(fmaxf(A*A*x2 + 2.f*A*Bc*xy + Bc*Bc*y2, 0.f));
      float rho = (n3 > MAXN) ? MAXN/n3 : 1.f;
      float nv  = fminf(n3, MAXN);
      float nvc = fmaxf(nv, MINN);
      float lam = art_(SQC*nvc)/(SQC*nvc);
      float lr  = lam*rho;
      th_wte = lr*(A*s*pq[1] + Bc*ws[710]);
      th_wth = lr*(A*s*pq[2] + Bc*ws[711]);
    }

    // ---- E branch ----
    float d1, d2;
    {
      float x0e[32];
#pragma unroll
      for(int c=0;c<32;++c) x0e[c] = x[((size_t)b*32 + c)*128 + s0 + t];
      stream_q<32,32,20>(We1 + s80*32, ring, t, 640, x0e,
        [&](int i,float a0,float a1,float a2,float a3){
          const float* bb = be1 + s80 + i;
          *(float4*)(ACT + t*132 + s80 + i) = make_float4(
            fmaxf(a0+bb[0],0.f), fmaxf(a1+bb[1],0.f),
            fmaxf(a2+bb[2],0.f), fmaxf(a3+bb[3],0.f));
        });
      __syncthreads();   // E1 acts ready

      float xin[80];
#pragma unroll
      for(int k=0;k<80;k+=4){
        float4 v = *(const float4*)(ACT + t*132 + k);
        xin[k]=v.x; xin[k+1]=v.y; xin[k+2]=v.z; xin[k+3]=v.w;
      }
      float r[28];
      stream_q<80,128,28>(We2 + s104*80, ring, t, (104-s104)*128, xin,
        [&](int i,float a0,float a1,float a2,float a3){
          const float* bb = be2 + s104 + i;
          r[i  ] = fmaxf(a0+bb[0],0.f);
          r[i+1] = fmaxf(a1+bb[1],0.f);
          r[i+2] = fmaxf(a2+bb[2],0.f);
          r[i+3] = fmaxf(a3+bb[3],0.f);
        });
      __syncthreads();   // all E2 readbacks done
#pragma unroll
      for(int i=0;i<28;i+=4)
        *(float4*)(ACT + t*132 + s104 + i) = make_float4(r[i],r[i+1],r[i+2],r[i+3]);
      __syncthreads();   // E2 acts ready

      float xin3[104];
#pragma unroll
      for(int k=0;k<104;k+=4){
        float4 v = *(const float4*)(ACT + t*132 + k);
        xin3[k]=v.x; xin3[k+1]=v.y; xin3[k+2]=v.z; xin3[k+3]=v.w;
      }
      float r3[32]; float pd[2] = {0.f,0.f};
      stream_q<104,128,32>(We3 + s128*104, ring, t, 4096, xin3,
        [&](int i,float a0,float a1,float a2,float a3){
          const float* bb = be3 + s128 + i;
          float v0 = fmaxf(a0+bb[0],0.f);
          float v1 = fmaxf(a1+bb[1],0.f);
          float v2 = fmaxf(a2+bb[2],0.f);
          float v3 = fmaxf(a3+bb[3],0.f);
          r3[i]=v0; r3[i+1]=v1; r3[i+2]=v2; r3[i+3]=v3;
          const float* U1 = u1 + s128 + i;
          const float* U2 = u2 + s128 + i;
          pd[0] = fmaf(v3,U1[3], fmaf(v2,U1[2], fmaf(v1,U1[1], fmaf(v0,U1[0], pd[0]))));
          pd[1] = fmaf(v3,U2[3], fmaf(v2,U2[2], fmaf(v1,U2[1], fmaf(v0,U2[0], pd[1]))));
        });
      exch<2>(PEX,w,t,0,pd);
      d1 = pd[0]; d2 = pd[1];
#pragma unroll
      for(int i=0;i<32;i+=4)
        *(float4*)(ACT + t*132 + s128 + i) = make_float4(r3[i],r3[i+1],r3[i+2],r3[i+3]);
    }

    // ---- attention finalize (redundant per wave; wave0 publishes) ----
    {
      float te1 = d1 + ws[704];
      float te2 = d2 + ws[705];
      float a_e = 0.5f*(te1 - th_wte) + bte[0];
      float a_h = 0.5f*(th_wth - te2) + bth[0];
      float mx_ = fmaxf(a_e, a_h);
      float ee = __expf(a_e - mx_), eh = __expf(a_h - mx_);
      float inv = 1.f/(ee + eh);
      float wge = ee*inv, wgh = eh*inv;
      float inner = wgh * rr;
      float scl2  = tanh_(inner)/(xnh*SQC);
      float nn    = scl2*xnh;
      if(nn > MAXN){ scl2 *= MAXN/nn; nn = MAXN; }
      float nnc  = fmaxf(nn, MINN);
      float lam2 = art_(SQC*nnc)/(SQC*nnc);
      if(w==0){ WG[t] = wge; WG[64+t] = lam2*scl2; }
    }
    __syncthreads();   // WG + out_e ready

    // ---- pooling: thread = feature pj, token-half phalf ----
#pragma unroll 4
    for(int q2=0;q2<32;++q2){
      const int tt = (phalf<<5) + q2;
      float wg = WG[tt], gg = WG[64+tt];
      poe = fmaf(wg, ACT[tt*132 + pj], poe);
      float hv = WSPARK ? pk[tt*PSTR + pj] : lpark[tt*PSTR + pj];
      poh = fmaf(gg, hv, poh);
    }
  } // tile loop

  // ---- combine pooling halves + classifier ----
  PV[(phalf<<8) + pj]       = poe;
  PV[(phalf<<8) + 128 + pj] = poh;
  __syncthreads();
  if(tid < 128){
    constexpr float inv128 = 1.f/128.f;
    OV[tid]     = (PV[tid]     + PV[256+tid]) * inv128;
    OV[128+tid] = (PV[128+tid] + PV[384+tid]) * inv128;
  }
  __syncthreads();
  if(w == 0){
    float f1v[10];
#pragma unroll
    for(int i=0;i<10;++i){
      float p = 0.f;
#pragma unroll
      for(int m=0;m<4;++m){ int k = t + (m<<6); p = fmaf(Wf1[i*256+k], OV[k], p); }
      f1v[i] = fmaxf(wsum(p) + bf1[i], 0.f);
    }
    if(t < 10){
      float o2 = bf2[t];
#pragma unroll
      for(int k=0;k<10;++k) o2 = fmaf(Wf2[t*10+k], f1v[k], o2);
      out[b*10 + t] = o2;
    }
  }
}

extern "C" void kernel_launch(void* const* d_in, const int* in_sizes, int n_in,
                              void* d_out, int out_size, void* d_ws, size_t ws_size,
                              hipStream_t stream){
  (void)in_sizes; (void)n_in; (void)out_size;
  const float* x   = (const float*)d_in[0];
  const float* We1 = (const float*)d_in[1];
  const float* be1 = (const float*)d_in[2];
  const float* We2 = (const float*)d_in[3];
  const float* be2 = (const float*)d_in[4];
  const float* We3 = (const float*)d_in[5];
  const float* be3 = (const float*)d_in[6];
  const float* Wh1 = (const float*)d_in[7];
  const float* bh1 = (const float*)d_in[8];
  const float* Wh2 = (const float*)d_in[9];
  const float* bh2 = (const float*)d_in[10];
  const float* Wh3 = (const float*)d_in[11];
  const float* bh3 = (const float*)d_in[12];
  const float* Wae = (const float*)d_in[13];
  const float* bae = (const float*)d_in[14];
  const float* Wah = (const float*)d_in[15];
  const float* bah = (const float*)d_in[16];
  const float* Wte = (const float*)d_in[17];
  const float* bte = (const float*)d_in[18];
  const float* Wth = (const float*)d_in[19];
  const float* bth = (const float*)d_in[20];
  const float* Wf1 = (const float*)d_in[21];
  const float* bf1 = (const float*)d_in[22];
  const float* Wf2 = (const float*)d_in[23];
  const float* bf2 = (const float*)d_in[24];
  float* ws  = (float*)d_ws;
  float* out = (float*)d_out;

  hipLaunchKernelGGL(k_setup, dim3(1), dim3(256), 0, stream,
                     Wae, bae, bh1, bh2, bh3, bah, Wte, Wth, be2, ws);

  // park region: 1024 rows * 2 tiles * 64 tok * 128 feat floats after ws[1024]
  const size_t need = (1024ull + 1024ull*2*64*128) * 4ull;
  if(ws_size >= need){
    const int smem = L_TOT*4;
    hipFuncSetAttribute((const void*)k_main<true>,
                        hipFuncAttributeMaxDynamicSharedMemorySize, smem);
    hipLaunchKernelGGL((k_main<true>), dim3(1024), dim3(256), smem, stream,
                       x, We1,be1, We2, We3,be3, Wh1,Wh2,Wh3, Wah,
                       Wte,bte, Wth,bth, Wf1,bf1, Wf2,bf2, ws, ws+1024, out);
  } else {
    const int smem = (L_TOT + 64*132)*4;
    hipFuncSetAttribute((const void*)k_main<false>,
                        hipFuncAttributeMaxDynamicSharedMemorySize, smem);
    hipLaunchKernelGGL((k_main<false>), dim3(1024), dim3(256), smem, stream,
                       x, We1,be1, We2, We3,be3, Wh1,Wh2,Wh3, Wah,
                       Wte,bte, Wth,bth, Wf1,bf1, Wf2,bf2, ws, (float*)nullptr, out);
  }
}

// Round 5
// 661.009 us; speedup vs baseline: 13.5971x; 13.5971x over previous
//
#include <hip/hip_runtime.h>
#include <math.h>

typedef float v2 __attribute__((ext_vector_type(2)));

constexpr float CC   = 1.2f;
constexpr float SQC  = 1.09544511501033215f;      // sqrt(1.2)
constexpr float MAXN = (1.0f - 4e-3f) / SQC;      // geoopt projx maxnorm
constexpr float MINN = 1e-15f;

// ---------------- scalar math helpers ----------------
__device__ __forceinline__ float art_(float x){
  x = fminf(fmaxf(x, -0.9999999f), 0.9999999f);
  return 0.5f * __logf((1.0f + x) / (1.0f - x));
}
__device__ __forceinline__ float tanh_(float x){
  x = fminf(fmaxf(x, -15.0f), 15.0f);
  float e = __expf(2.0f * x);
  return (e - 1.0f) / (e + 1.0f);
}
__device__ __forceinline__ float wsum(float v){
#pragma unroll
  for(int i=32;i>0;i>>=1) v += __shfl_xor(v, i, 64);
  return v;
}
__device__ __forceinline__ float lamv(float nv){
  float n = fmaxf(nv, MINN);
  return art_(SQC*n)/(SQC*n);
}

// ---------------- packed (2-token) helpers ----------------
__device__ __forceinline__ v2 v2s(float s){ v2 r; r.x=s; r.y=s; return r; }
__device__ __forceinline__ v2 fmav(v2 a, v2 b, v2 c){ return __builtin_elementwise_fma(a,b,c); }
__device__ __forceinline__ v2 fma2(float w, v2 x, v2 a){ return __builtin_elementwise_fma(v2s(w),x,a); }
__device__ __forceinline__ v2 max0(v2 a){ v2 r; r.x=fmaxf(a.x,0.f); r.y=fmaxf(a.y,0.f); return r; }

struct HS { float ca, cb, nv; };
__device__ __forceinline__ HS hyper_chain(float m2, float meb, float xn_in, float y2){
  float xn  = fmaxf(xn_in, MINN);
  float mxn = fmaxf(sqrtf(m2), MINN);
  float r   = art_(SQC*xn);
  float s   = tanh_(mxn/xn*r)/(mxn*SQC);
  float nr  = s*mxn;
  if(nr > MAXN){ s *= MAXN/nr; nr = MAXN; }
  float xy = s*meb, x2 = nr*nr;
  float den = fmaxf(1.f + 2.f*CC*xy + CC*CC*x2*y2, MINN);
  float A   = (1.f + 2.f*CC*xy + CC*y2)/den;
  float Bc  = (1.f - CC*x2)/den;
  float n3  = sqrtf(fmaxf(A*A*x2 + 2.f*A*Bc*xy + Bc*Bc*y2, 0.f));
  float rho = (n3 > MAXN) ? MAXN/n3 : 1.f;
  HS h; h.nv = fminf(n3, MAXN); h.ca = rho*A*s; h.cb = rho*Bc;
  return h;
}
struct TT { float tau, nf; };
__device__ __forceinline__ TT tail_relu(float rn2){
  float rn = fmaxf(sqrtf(rn2), MINN);
  float th = tanh_(SQC*rn);
  TT r; r.tau = th/(SQC*rn); r.nf = th/SQC;
  if(r.nf > MAXN){ r.tau *= MAXN/r.nf; r.nf = MAXN; }
  return r;
}
struct EX { float nh, scl; };
__device__ __forceinline__ EX exp0(float n2){
  float n0 = fmaxf(sqrtf(n2), MINN);
  float th = tanh_(SQC*n0);
  EX e; e.nh = th/SQC; e.scl = th/(SQC*n0);
  if(e.nh > MAXN){ e.scl *= MAXN/e.nh; e.nh = MAXN; }
  return e;
}
struct THW { float te, th2; };
__device__ __forceinline__ THW ahchain(float m2a, float mw1, float mw2, float meba,
                                       float xnh, float rr, const float* __restrict__ ws){
  float mxn = fmaxf(sqrtf(m2a), MINN);
  float s = tanh_(mxn/xnh*rr)/(mxn*SQC);
  float nr = s*mxn;
  if(nr > MAXN){ s *= MAXN/nr; nr = MAXN; }
  float xy = s*meba, x2 = nr*nr, y2 = ws[701];
  float den = fmaxf(1.f + 2.f*CC*xy + CC*CC*x2*y2, MINN);
  float A = (1.f + 2.f*CC*xy + CC*y2)/den;
  float Bc = (1.f - CC*x2)/den;
  float n3 = sqrtf(fmaxf(A*A*x2 + 2.f*A*Bc*xy + Bc*Bc*y2, 0.f));
  float rho = (n3 > MAXN) ? MAXN/n3 : 1.f;
  float nv = fminf(n3, MAXN);
  float lr = lamv(nv)*rho;
  THW r; r.te = lr*(A*s*mw1 + Bc*ws[702]); r.th2 = lr*(A*s*mw2 + Bc*ws[703]);
  return r;
}
struct AG { float wge, g2; };
__device__ __forceinline__ AG attn(float d1, float d2, float thte, float thth,
                                   float rr, float xnh, float c1, float c2,
                                   float b_e, float b_h){
  float a_e = 0.5f*((d1 + c1) - thte) + b_e;
  float a_h = 0.5f*(thth - (d2 + c2)) + b_h;
  float mx = fmaxf(a_e, a_h);
  float ee = __expf(a_e - mx), eh = __expf(a_h - mx);
  float inv = 1.f/(ee + eh);
  AG r; r.wge = ee*inv;
  float wgh = eh*inv;
  float inner = wgh*rr;
  float scl2 = tanh_(inner)/(xnh*SQC);
  float nn = scl2*xnh;
  if(nn > MAXN){ scl2 *= MAXN/nn; nn = MAXN; }
  r.g2 = lamv(nn)*scl2;
  return r;
}

// ---------------- setup kernel (folded constants into ws) ----------------
// ws: [0..127] u1=Wae^T Wte | [128..255] u2=Wae^T Wth | [256..335] eb1(80)
// [336..439] eb2(104) | [440..567] eb3(128) | [568..695] eba(128) |
// [696] c1 [697] c2 [698..701] y2h1,y2h2,y2h3,y2ah [702] EBW1 [703] EBW2
__global__ void k_setup(const float* __restrict__ Wae, const float* __restrict__ bae,
                        const float* __restrict__ bh1, const float* __restrict__ bh2,
                        const float* __restrict__ bh3, const float* __restrict__ bah,
                        const float* __restrict__ Wte, const float* __restrict__ Wth,
                        float* __restrict__ ws){
  const int tid = threadIdx.x;            // 256 threads, 1 block
  {
    const int which = tid >> 7, k = tid & 127;
    const float* wv = which ? Wth : Wte;
    float s = 0.f;
#pragma unroll 4
    for(int j=0;j<128;++j) s += Wae[j*128+k] * wv[j];
    ws[which*128 + k] = s;
  }
  if(tid < 64){
    const int l = tid;
    float p1=0.f, p2=0.f;
    for(int j=l;j<128;j+=64){ p1 += bae[j]*Wte[j]; p2 += bae[j]*Wth[j]; }
    p1 = wsum(p1); p2 = wsum(p2);
    if(l==0){ ws[696]=p1; ws[697]=p2; }
    const float* bs[4] = {bh1,bh2,bh3,bah};
    const int dims[4]  = {80,104,128,128};
    const int offs[4]  = {256,336,440,568};
    for(int v=0;v<4;++v){
      const float* bp = bs[v]; const int D = dims[v];
      float q = 0.f;
      for(int j=l;j<D;j+=64) q += bp[j]*bp[j];
      q = wsum(q);
      float nb = fmaxf(sqrtf(q), MINN);
      float th = tanhf(fminf(fmaxf(SQC*nb,-15.f),15.f));
      float coef = th/(SQC*nb);
      float ne = th/SQC;
      if(ne > MAXN){ coef *= MAXN/ne; ne = MAXN; }
      for(int j=l;j<D;j+=64) ws[offs[v]+j] = coef*bp[j];
      if(l==0) ws[698+v] = ne*ne;
      if(v==3){
        float e1=0.f, e2=0.f;
        for(int j=l;j<D;j+=64){ e1 += bp[j]*Wte[j]; e2 += bp[j]*Wth[j]; }
        e1 = wsum(e1)*coef; e2 = wsum(e2)*coef;
        if(l==0){ ws[702]=e1; ws[703]=e2; }
      }
    }
  }
}

// ---------------- weight streaming (global -> LDS ring -> broadcast reads) ----
__device__ __forceinline__ float4 f4z(){ return make_float4(0.f,0.f,0.f,0.f); }

// staging load; f = float index in KP-padded row-major space
template<int K,int KP>
__device__ __forceinline__ float4 ldst(const float* __restrict__ W, int f){
  if constexpr (K == KP){
    return *(const float4*)(W + f);
  } else {                         // KP == 128, K < 128
    const int col = f & 127;
    if(col >= K) return f4z();
    return *(const float4*)(W + (f >> 7)*K + col);
  }
}

// stream OUT rows of W[OUT][K]; per 4-row group call sink(jb, a0..a3) with
// v2 accumulators (token pair). Rows padded to KP in ring so 4*KP | 1024
// (no wrap inside a group, ds offsets are base+imm).
template<int K,int OUT,typename F>
__device__ __forceinline__ void stream_mv(const float* __restrict__ W,
                                          float* __restrict__ ring, const int t,
                                          const v2 (&xin)[K], F&& sink){
  constexpr int KP  = (K == 32) ? 32 : 128;
  constexpr int NCH = (OUT*KP) >> 9;
  constexpr int NG  = OUT >> 2;
  const int l4 = t << 2;
  float4 q0 = f4z(), q1 = f4z();
  {
    float4 p0 = ldst<K,KP>(W, l4);
    float4 p1 = ldst<K,KP>(W, l4 + 256);
    if(NCH > 1){
      q0 = ldst<K,KP>(W, 512 + l4);
      q1 = ldst<K,KP>(W, 512 + l4 + 256);
    }
    *(float4*)(ring + l4) = p0;
    *(float4*)(ring + 256 + l4) = p1;
  }
  int cm = 0, nl = 2;
  for(int g = 0; g < NG; ++g){
    const int need = ((g+1)*(4*KP) - 1) >> 9;
    if(cm < need){
      ++cm;
      float* dst = ring + ((cm & 1) << 9);
      *(float4*)(dst + l4) = q0;
      *(float4*)(dst + 256 + l4) = q1;
      if(nl < NCH){
        q0 = ldst<K,KP>(W, (nl << 9) + l4);
        q1 = ldst<K,KP>(W, (nl << 9) + l4 + 256);
      }
      ++nl;
    }
    const float* rg = ring + ((g*(4*KP)) & 1023);
    v2 a0 = v2s(0.f), a1 = v2s(0.f), a2 = v2s(0.f), a3 = v2s(0.f);
#pragma unroll
    for(int k = 0; k < K; k += 4){
      float4 w0 = *(const float4*)(rg + 0*KP + k);
      float4 w1 = *(const float4*)(rg + 1*KP + k);
      float4 w2 = *(const float4*)(rg + 2*KP + k);
      float4 w3 = *(const float4*)(rg + 3*KP + k);
      v2 xa = xin[k], xb = xin[k+1], xc = xin[k+2], xd = xin[k+3];
      a0 = fma2(w0.w,xd, fma2(w0.z,xc, fma2(w0.y,xb, fma2(w0.x,xa, a0))));
      a1 = fma2(w1.w,xd, fma2(w1.z,xc, fma2(w1.y,xb, fma2(w1.x,xa, a1))));
      a2 = fma2(w2.w,xd, fma2(w2.z,xc, fma2(w2.y,xb, fma2(w2.x,xa, a2))));
      a3 = fma2(w3.w,xd, fma2(w3.z,xc, fma2(w3.y,xb, fma2(w3.x,xa, a3))));
    }
    sink(g << 2, a0, a1, a2, a3);
  }
}

// ---------------- hyperbolic layer (p_linear [+ mob_relu]) ----------------
// raw outputs: rows 0..63 staged via BUF then copied to xout; rows 64.. via BUF.
template<int K,int OUT,bool MRELU>
__device__ __forceinline__ v2 hlayer(const float* __restrict__ W, const float* __restrict__ eb,
                                     float y2, v2 xn, v2 ca_pre,
                                     const v2 (&xin)[K], v2 (&xout)[OUT],
                                     float* __restrict__ ring, v2* __restrict__ BUF, int t){
  v2 m2 = v2s(0.f), meb = v2s(0.f);
  auto s1 = [&](int jb, v2 a0, v2 a1, v2 a2, v2 a3){
    m2 = fmav(a3,a3, fmav(a2,a2, fmav(a1,a1, fmav(a0,a0, m2))));
    float4 e = *(const float4*)(eb + jb);
    meb = fma2(e.x,a0, fma2(e.y,a1, fma2(e.z,a2, fma2(e.w,a3, meb))));
    BUF[(jb+0)*64+t]=a0; BUF[(jb+1)*64+t]=a1; BUF[(jb+2)*64+t]=a2; BUF[(jb+3)*64+t]=a3;
  };
  stream_mv<K,64>(W, ring, t, xin, s1);
#pragma unroll
  for(int f=0; f<64; ++f) xout[f] = BUF[f*64+t];        // raw, rows 0..63
  auto s2 = [&](int jb, v2 a0, v2 a1, v2 a2, v2 a3){
    m2 = fmav(a3,a3, fmav(a2,a2, fmav(a1,a1, fmav(a0,a0, m2))));
    float4 e = *(const float4*)(eb + 64 + jb);
    meb = fma2(e.x,a0, fma2(e.y,a1, fma2(e.z,a2, fma2(e.w,a3, meb))));
    BUF[(jb+0)*64+t]=a0; BUF[(jb+1)*64+t]=a1; BUF[(jb+2)*64+t]=a2; BUF[(jb+3)*64+t]=a3;
  };
  stream_mv<K,OUT-64>(W + 64*K, ring, t, xin, s2);
#pragma unroll
  for(int f=64; f<OUT; ++f) xout[f] = BUF[(f-64)*64+t]; // raw, rows 64..
  // scalar chain (input-scale folded via ca_pre)
  m2 = m2*(ca_pre*ca_pre); meb = meb*ca_pre;
  HS hx = hyper_chain(m2.x, meb.x, xn.x, y2);
  HS hy = hyper_chain(m2.y, meb.y, xn.y, y2);
  v2 ca; ca.x = hx.ca; ca.y = hy.ca; ca = ca*ca_pre;
  v2 cb; cb.x = hx.cb; cb.y = hy.cb;
  if(MRELU){
    v2 lam; lam.x = lamv(hx.nv); lam.y = lamv(hy.nv);
    v2 rn2 = v2s(0.f);
#pragma unroll
    for(int f=0; f<OUT; ++f){
      v2 v = fmav(ca, xout[f], cb*v2s(eb[f]));
      v2 r = max0(lam*v);
      rn2 = fmav(r,r,rn2);
      xout[f] = r;
    }
    TT tx = tail_relu(rn2.x), ty = tail_relu(rn2.y);
    v2 tau; tau.x = tx.tau; tau.y = ty.tau;
#pragma unroll
    for(int f=0; f<OUT; ++f) xout[f] = xout[f]*tau;
    v2 nf; nf.x = tx.nf; nf.y = ty.nf;
    return nf;
  } else {
#pragma unroll
    for(int f=0; f<OUT; ++f) xout[f] = fmav(ca, xout[f], cb*v2s(eb[f]));
    v2 nv; nv.x = fmaxf(hx.nv, MINN); nv.y = fmaxf(hy.nv, MINN);
    return nv;
  }
}

// ---------------- euclidean layer (relu(Wx+b)) ----------------
template<int K,int OUT>
__device__ __forceinline__ void elayer(const float* __restrict__ W, const float* __restrict__ be,
                                       const v2 (&xin)[K], v2 (&xout)[OUT],
                                       float* __restrict__ ring, v2* __restrict__ BUF, int t){
  auto s1 = [&](int jb, v2 a0, v2 a1, v2 a2, v2 a3){
    float4 bb = *(const float4*)(be + jb);
    BUF[(jb+0)*64+t]=max0(a0+v2s(bb.x)); BUF[(jb+1)*64+t]=max0(a1+v2s(bb.y));
    BUF[(jb+2)*64+t]=max0(a2+v2s(bb.z)); BUF[(jb+3)*64+t]=max0(a3+v2s(bb.w));
  };
  stream_mv<K,64>(W, ring, t, xin, s1);
#pragma unroll
  for(int f=0; f<64; ++f) xout[f] = BUF[f*64+t];
  auto s2 = [&](int jb, v2 a0, v2 a1, v2 a2, v2 a3){
    float4 bb = *(const float4*)(be + 64 + jb);
    BUF[(jb+0)*64+t]=max0(a0+v2s(bb.x)); BUF[(jb+1)*64+t]=max0(a1+v2s(bb.y));
    BUF[(jb+2)*64+t]=max0(a2+v2s(bb.z)); BUF[(jb+3)*64+t]=max0(a3+v2s(bb.w));
  };
  stream_mv<K,OUT-64>(W + 64*K, ring, t, xin, s2);
#pragma unroll
  for(int f=64; f<OUT; ++f) xout[f] = BUF[(f-64)*64+t];
}

// ---------------- main kernel: 1 block = 1 wave = 1 batch row -------------
// lane t owns the token PAIR (t, t+64) packed in v2. Single pass, no tiles.
// LDS: ring[1024] floats + BUF[64 feat][64 lanes] v2 = 36,864 B -> 4 blocks/CU.
__global__ __launch_bounds__(64, 1) void k_main(
    const float* __restrict__ x,
    const float* __restrict__ We1, const float* __restrict__ be1,
    const float* __restrict__ We2, const float* __restrict__ be2,
    const float* __restrict__ We3, const float* __restrict__ be3,
    const float* __restrict__ Wh1, const float* __restrict__ Wh2,
    const float* __restrict__ Wh3, const float* __restrict__ Wah,
    const float* __restrict__ Wte, const float* __restrict__ bte,
    const float* __restrict__ Wth, const float* __restrict__ bth,
    const float* __restrict__ Wf1, const float* __restrict__ bf1,
    const float* __restrict__ Wf2, const float* __restrict__ bf2,
    const float* __restrict__ ws, float* __restrict__ out){
  extern __shared__ float lds[];
  float* ring = lds;                 // 1024 floats
  v2* BUF = (v2*)(lds + 1024);       // 64*64 v2
  const int t = threadIdx.x, b = blockIdx.x;
  v2 one = v2s(1.f);

  // ---- x0 token pair + expmap0 scalars ----
  v2 x0[32];
#pragma unroll
  for(int c=0;c<32;++c){
    const float* px = x + ((size_t)b*32 + c)*128 + t;
    v2 xv; xv.x = px[0]; xv.y = px[64]; x0[c] = xv;
  }
  v2 n2 = v2s(0.f);
#pragma unroll
  for(int c=0;c<32;++c) n2 = fmav(x0[c], x0[c], n2);
  EX ex0 = exp0(n2.x), ey0 = exp0(n2.y);
  v2 nh;  nh.x = ex0.nh;  nh.y = ey0.nh;
  v2 scl; scl.x = ex0.scl; scl.y = ey0.scl;

  // ---- Poincare branch ----
  v2 xh1[80];
  v2 nf1 = hlayer<32,80,true >(Wh1, ws+256, ws[698], nh,  scl, x0,  xh1, ring, BUF, t);
  v2 xh2[104];
  v2 nf2 = hlayer<80,104,true>(Wh2, ws+336, ws[699], nf1, one, xh1, xh2, ring, BUF, t);
  v2 oh[128];
  v2 xnh = hlayer<104,128,false>(Wh3, ws+440, ws[700], nf2, one, xh2, oh, ring, BUF, t);
  v2 rr; rr.x = art_(SQC*xnh.x); rr.y = art_(SQC*xnh.y);

  // zh[i] = Wf1[i, 128:256] . out_h  (classifier fold, hyperbolic half)
  v2 zh[10];
#pragma unroll
  for(int i=0;i<10;++i){
    v2 acc = v2s(0.f);
#pragma unroll
    for(int f=0; f<128; f+=4){
      float4 wv = *(const float4*)(Wf1 + i*256 + 128 + f);
      acc = fma2(wv.x,oh[f], fma2(wv.y,oh[f+1], fma2(wv.z,oh[f+2], fma2(wv.w,oh[f+3], acc))));
    }
    zh[i] = acc;
  }

  // Wah pass: 4 reductions of mx = Wah . out_h
  v2 m2a = v2s(0.f), mw1 = v2s(0.f), mw2 = v2s(0.f), meba = v2s(0.f);
  stream_mv<128,128>(Wah, ring, t, oh, [&](int jb, v2 a0, v2 a1, v2 a2, v2 a3){
    m2a = fmav(a3,a3, fmav(a2,a2, fmav(a1,a1, fmav(a0,a0, m2a))));
    float4 w1v = *(const float4*)(Wte + jb);
    mw1 = fma2(w1v.x,a0, fma2(w1v.y,a1, fma2(w1v.z,a2, fma2(w1v.w,a3, mw1))));
    float4 w2v = *(const float4*)(Wth + jb);
    mw2 = fma2(w2v.x,a0, fma2(w2v.y,a1, fma2(w2v.z,a2, fma2(w2v.w,a3, mw2))));
    float4 ev = *(const float4*)(ws + 568 + jb);
    meba = fma2(ev.x,a0, fma2(ev.y,a1, fma2(ev.z,a2, fma2(ev.w,a3, meba))));
  });
  THW ax = ahchain(m2a.x, mw1.x, mw2.x, meba.x, xnh.x, rr.x, ws);
  THW ay = ahchain(m2a.y, mw1.y, mw2.y, meba.y, xnh.y, rr.y, ws);

  // ---- Euclidean branch ----
  v2 x0e[32];
#pragma unroll
  for(int c=0;c<32;++c){
    const float* px = x + ((size_t)b*32 + c)*128 + t;
    v2 xv; xv.x = px[0]; xv.y = px[64]; x0e[c] = xv;
  }
  v2 xe1[80];  elayer<32,80 >(We1, be1, x0e, xe1, ring, BUF, t);
  v2 xe2[104]; elayer<80,104>(We2, be2, xe1, xe2, ring, BUF, t);

  v2 d1 = v2s(0.f), d2 = v2s(0.f);
  v2 ze[10];
#pragma unroll
  for(int i=0;i<10;++i) ze[i] = v2s(0.f);
  stream_mv<104,128>(We3, ring, t, xe2, [&](int jb, v2 a0, v2 a1, v2 a2, v2 a3){
    float4 bb = *(const float4*)(be3 + jb);
    v2 o0 = max0(a0 + v2s(bb.x)); v2 o1 = max0(a1 + v2s(bb.y));
    v2 o2 = max0(a2 + v2s(bb.z)); v2 o3 = max0(a3 + v2s(bb.w));
    float4 uu = *(const float4*)(ws + jb);        // u1
    d1 = fma2(uu.x,o0, fma2(uu.y,o1, fma2(uu.z,o2, fma2(uu.w,o3, d1))));
    float4 vv = *(const float4*)(ws + 128 + jb);  // u2
    d2 = fma2(vv.x,o0, fma2(vv.y,o1, fma2(vv.z,o2, fma2(vv.w,o3, d2))));
#pragma unroll
    for(int i=0;i<10;++i){
      float4 wf = *(const float4*)(Wf1 + i*256 + jb);
      ze[i] = fma2(wf.x,o0, fma2(wf.y,o1, fma2(wf.z,o2, fma2(wf.w,o3, ze[i]))));
    }
  });

  // ---- attention + pooled classifier partials (per token pair) ----
  AG gx = attn(d1.x, d2.x, ax.te, ax.th2, rr.x, xnh.x, ws[696], ws[697], bte[0], bth[0]);
  AG gy = attn(d1.y, d2.y, ay.te, ay.th2, rr.y, xnh.y, ws[696], ws[697], bte[0], bth[0]);

  float f1v[10];
#pragma unroll
  for(int i=0;i<10;++i){
    float p = fmaf(gx.wge, ze[i].x, fmaf(gy.wge, ze[i].y,
              fmaf(gx.g2,  zh[i].x, gy.g2 * zh[i].y)));
    f1v[i] = fmaxf(wsum(p)*(1.f/128.f) + bf1[i], 0.f);
  }
  if(t < 10){
    float o2 = bf2[t];
#pragma unroll
    for(int k=0;k<10;++k) o2 = fmaf(Wf2[t*10+k], f1v[k], o2);
    out[b*10 + t] = o2;
  }
}

extern "C" void kernel_launch(void* const* d_in, const int* in_sizes, int n_in,
                              void* d_out, int out_size, void* d_ws, size_t ws_size,
                              hipStream_t stream){
  (void)in_sizes; (void)n_in; (void)out_size; (void)ws_size;
  const float* x   = (const float*)d_in[0];
  const float* We1 = (const float*)d_in[1];
  const float* be1 = (const float*)d_in[2];
  const float* We2 = (const float*)d_in[3];
  const float* be2 = (const float*)d_in[4];
  const float* We3 = (const float*)d_in[5];
  const float* be3 = (const float*)d_in[6];
  const float* Wh1 = (const float*)d_in[7];
  const float* bh1 = (const float*)d_in[8];
  const float* Wh2 = (const float*)d_in[9];
  const float* bh2 = (const float*)d_in[10];
  const float* Wh3 = (const float*)d_in[11];
  const float* bh3 = (const float*)d_in[12];
  const float* Wae = (const float*)d_in[13];
  const float* bae = (const float*)d_in[14];
  const float* Wah = (const float*)d_in[15];
  const float* bah = (const float*)d_in[16];
  const float* Wte = (const float*)d_in[17];
  const float* bte = (const float*)d_in[18];
  const float* Wth = (const float*)d_in[19];
  const float* bth = (const float*)d_in[20];
  const float* Wf1 = (const float*)d_in[21];
  const float* bf1 = (const float*)d_in[22];
  const float* Wf2 = (const float*)d_in[23];
  const float* bf2 = (const float*)d_in[24];
  float* ws  = (float*)d_ws;
  float* out = (float*)d_out;

  hipLaunchKernelGGL(k_setup, dim3(1), dim3(256), 0, stream,
                     Wae, bae, bh1, bh2, bh3, bah, Wte, Wth, ws);

  const int smem = (1024 + 64*64*2) * 4;   // ring + BUF = 36,864 B
  hipLaunchKernelGGL(k_main, dim3(1024), dim3(64), smem, stream,
                     x, We1,be1, We2,be2, We3,be3, Wh1,Wh2,Wh3, Wah,
                     Wte,bte, Wth,bth, Wf1,bf1, Wf2,bf2, ws, out);
}

// Round 6
// 620.893 us; speedup vs baseline: 14.4756x; 1.0646x over previous
//
#include <hip/hip_runtime.h>
#include <math.h>

constexpr float CC   = 1.2f;
constexpr float SQC  = 1.09544511501033215f;      // sqrt(1.2)
constexpr float MAXN = (1.0f - 4e-3f) / SQC;      // geoopt projx maxnorm
constexpr float MINN = 1e-15f;

// ---------------- ws float offsets (transposed padded weights + constants) ----
constexpr int WTH1 = 0;        // [32][128]
constexpr int WTH2 = 4096;     // [80][128]
constexpr int WTH3 = 14336;    // [104][128]
constexpr int WTAH = 27648;    // [128][128]
constexpr int WTE1 = 44032;    // [32][128]
constexpr int WTE2 = 48128;    // [80][128]
constexpr int WTE3 = 58368;    // [104][128]
constexpr int EB1  = 71680;    // expmap0(bh1) padded 128
constexpr int EB2  = 71808;
constexpr int EB3  = 71936;
constexpr int EBA  = 72064;
constexpr int BE1  = 72192;    // be1 padded 128
constexpr int BE2  = 72320;
constexpr int BE3  = 72448;
constexpr int U1o  = 72576;    // Wae^T wte
constexpr int U2o  = 72704;    // Wae^T wth
constexpr int SCo  = 72832;    // c1,c2,y2h1,y2h2,y2h3,y2ah,EBW1,EBW2

// ---------------- LDS float offsets ----------------
constexpr int ASTR  = 129;     // ACT row stride (bank-spread)
constexpr int L_ACT = 0;       // 128*129 = 16512
constexpr int L_ZH  = 16512;   // 10*128
constexpr int L_SCR = 17792;   // 12*128 scratch slots
constexpr int L_F1  = 19328;   // 16
constexpr int L_TOT = 19344;   // 77,376 B -> 2 blocks/CU (8 waves/CU)

// ---------------- scalar math ----------------
__device__ __forceinline__ float art_(float x){
  x = fminf(fmaxf(x, -0.9999999f), 0.9999999f);
  return 0.5f * __logf((1.0f + x) / (1.0f - x));
}
__device__ __forceinline__ float tanh_(float x){
  x = fminf(fmaxf(x, -15.0f), 15.0f);
  float e = __expf(2.0f * x);
  return (e - 1.0f) / (e + 1.0f);
}
__device__ __forceinline__ float wsum(float v){
#pragma unroll
  for(int i=32;i>0;i>>=1) v += __shfl_xor(v, i, 64);
  return v;
}
__device__ __forceinline__ float rtj(float v){   // sum over the 16 tj lanes
  v += __shfl_xor(v, 1, 64); v += __shfl_xor(v, 2, 64);
  v += __shfl_xor(v, 4, 64); v += __shfl_xor(v, 8, 64);
  return v;
}
__device__ __forceinline__ float lamv(float nv){
  float n = fmaxf(nv, MINN);
  return art_(SQC*n)/(SQC*n);
}
struct HS { float ca, cb, nv; };
__device__ __forceinline__ HS hyper_chain(float m2, float meb, float xn_in, float y2){
  float xn  = fmaxf(xn_in, MINN);
  float mxn = fmaxf(sqrtf(m2), MINN);
  float r   = art_(SQC*xn);
  float s   = tanh_(mxn/xn*r)/(mxn*SQC);
  float nr  = s*mxn;
  if(nr > MAXN){ s *= MAXN/nr; nr = MAXN; }
  float xy = s*meb, x2 = nr*nr;
  float den = fmaxf(1.f + 2.f*CC*xy + CC*CC*x2*y2, MINN);
  float A   = (1.f + 2.f*CC*xy + CC*y2)/den;
  float Bc  = (1.f - CC*x2)/den;
  float n3  = sqrtf(fmaxf(A*A*x2 + 2.f*A*Bc*xy + Bc*Bc*y2, 0.f));
  float rho = (n3 > MAXN) ? MAXN/n3 : 1.f;
  HS h; h.nv = fminf(n3, MAXN); h.ca = rho*A*s; h.cb = rho*Bc;
  return h;
}
struct TT { float tau, nf; };
__device__ __forceinline__ TT tail_relu(float rn2){
  float rn = fmaxf(sqrtf(rn2), MINN);
  float th = tanh_(SQC*rn);
  TT r; r.tau = th/(SQC*rn); r.nf = th/SQC;
  if(r.nf > MAXN){ r.tau *= MAXN/r.nf; r.nf = MAXN; }
  return r;
}
struct EX { float nh, scl; };
__device__ __forceinline__ EX exp0(float n2){
  float n0 = fmaxf(sqrtf(n2), MINN);
  float th = tanh_(SQC*n0);
  EX e; e.nh = th/SQC; e.scl = th/(SQC*n0);
  if(e.nh > MAXN){ e.scl *= MAXN/e.nh; e.nh = MAXN; }
  return e;
}
struct THW { float te, th2; };
__device__ __forceinline__ THW ahchain(float m2a, float mw1, float mw2, float meba,
                                       float xnh, float rr, float y2,
                                       float ebw1, float ebw2){
  float mxn = fmaxf(sqrtf(m2a), MINN);
  float s = tanh_(mxn/xnh*rr)/(mxn*SQC);
  float nr = s*mxn;
  if(nr > MAXN){ s *= MAXN/nr; nr = MAXN; }
  float xy = s*meba, x2 = nr*nr;
  float den = fmaxf(1.f + 2.f*CC*xy + CC*CC*x2*y2, MINN);
  float A = (1.f + 2.f*CC*xy + CC*y2)/den;
  float Bc = (1.f - CC*x2)/den;
  float n3 = sqrtf(fmaxf(A*A*x2 + 2.f*A*Bc*xy + Bc*Bc*y2, 0.f));
  float rho = (n3 > MAXN) ? MAXN/n3 : 1.f;
  float nv = fminf(n3, MAXN);
  float lr = lamv(nv)*rho;
  THW r; r.te = lr*(A*s*mw1 + Bc*ebw1); r.th2 = lr*(A*s*mw2 + Bc*ebw2);
  return r;
}
struct AG { float wge, g2; };
__device__ __forceinline__ AG attn(float d1, float d2, float thte, float thth,
                                   float rr, float xnh, float b_e, float b_h){
  float a_e = 0.5f*(d1 - thte) + b_e;
  float a_h = 0.5f*(thth - d2) + b_h;
  float mx = fmaxf(a_e, a_h);
  float ee = __expf(a_e - mx), eh = __expf(a_h - mx);
  float inv = 1.f/(ee + eh);
  AG r; r.wge = ee*inv;
  float wgh = eh*inv;
  float inner = wgh*rr;
  float scl2 = tanh_(inner)/(xnh*SQC);
  float nn = scl2*xnh;
  if(nn > MAXN){ scl2 *= MAXN/nn; nn = MAXN; }
  r.g2 = lamv(nn)*scl2;
  return r;
}

// ---------------- setup A: folded constants ----------------
__global__ void k_setup_a(const float* __restrict__ Wae, const float* __restrict__ bae,
                          const float* __restrict__ bh1, const float* __restrict__ bh2,
                          const float* __restrict__ bh3, const float* __restrict__ bah,
                          const float* __restrict__ Wte, const float* __restrict__ Wth,
                          const float* __restrict__ be1, const float* __restrict__ be2,
                          const float* __restrict__ be3, float* __restrict__ ws){
  const int tid = threadIdx.x;            // 256 threads, 1 block
  {
    const int which = tid >> 7, k = tid & 127;
    const float* wv = which ? Wth : Wte;
    float s = 0.f;
#pragma unroll 4
    for(int j=0;j<128;++j) s += Wae[j*128+k] * wv[j];
    ws[(which ? U2o : U1o) + k] = s;
  }
  // padded biases
  if(tid < 128){
    ws[BE1+tid] = (tid < 80)  ? be1[tid] : 0.f;
    ws[BE2+tid] = (tid < 104) ? be2[tid] : 0.f;
    ws[BE3+tid] = be3[tid];
  }
  if(tid < 64){
    const int l = tid;
    float p1=0.f, p2=0.f;
    for(int j=l;j<128;j+=64){ p1 += bae[j]*Wte[j]; p2 += bae[j]*Wth[j]; }
    p1 = wsum(p1); p2 = wsum(p2);
    if(l==0){ ws[SCo+0]=p1; ws[SCo+1]=p2; }
    const float* bs[4] = {bh1,bh2,bh3,bah};
    const int dims[4]  = {80,104,128,128};
    const int offs[4]  = {EB1,EB2,EB3,EBA};
    for(int v=0;v<4;++v){
      const float* bp = bs[v]; const int D = dims[v];
      float q = 0.f;
      for(int j=l;j<D;j+=64) q += bp[j]*bp[j];
      q = wsum(q);
      float nb = fmaxf(sqrtf(q), MINN);
      float th = tanhf(fminf(fmaxf(SQC*nb,-15.f),15.f));
      float coef = th/(SQC*nb);
      float ne = th/SQC;
      if(ne > MAXN){ coef *= MAXN/ne; ne = MAXN; }
      for(int j=l;j<D;j+=64) ws[offs[v]+j] = coef*bp[j];
      for(int j=D+l;j<128;j+=64) ws[offs[v]+j] = 0.f;   // pad
      if(l==0) ws[SCo+2+v] = ne*ne;
      if(v==3){
        float e1=0.f, e2=0.f;
        for(int j=l;j<D;j+=64){ e1 += bp[j]*Wte[j]; e2 += bp[j]*Wth[j]; }
        e1 = wsum(e1)*coef; e2 = wsum(e2)*coef;
        if(l==0){ ws[SCo+6]=e1; ws[SCo+7]=e2; }
      }
    }
  }
}

// ---------------- setup B: transpose + pad weights into ws (k-major) --------
__global__ void k_trans(const float* __restrict__ Wh1, const float* __restrict__ Wh2,
                        const float* __restrict__ Wh3, const float* __restrict__ Wah,
                        const float* __restrict__ We1, const float* __restrict__ We2,
                        const float* __restrict__ We3, float* __restrict__ ws){
  const int blk = blockIdx.x, j = threadIdx.x;   // grid 560, block 128
  const float* W; int OUT, K, kk, dst;
  if(blk < 32)       { W=Wh1; OUT=80;  K=32;  kk=blk;      dst=WTH1; }
  else if(blk < 112) { W=Wh2; OUT=104; K=80;  kk=blk-32;   dst=WTH2; }
  else if(blk < 216) { W=Wh3; OUT=128; K=104; kk=blk-112;  dst=WTH3; }
  else if(blk < 344) { W=Wah; OUT=128; K=128; kk=blk-216;  dst=WTAH; }
  else if(blk < 376) { W=We1; OUT=80;  K=32;  kk=blk-344;  dst=WTE1; }
  else if(blk < 456) { W=We2; OUT=104; K=80;  kk=blk-376;  dst=WTE2; }
  else               { W=We3; OUT=128; K=104; kk=blk-456;  dst=WTE3; }
  ws[dst + kk*128 + j] = (j < OUT) ? W[j*K + kk] : 0.f;
}

// ---------------- GEMM inner: 8x8 register tile per thread ----------------
__device__ __forceinline__ void ld8(const float* __restrict__ p, float (&v)[8]){
  float4 a = *(const float4*)p, b = *(const float4*)(p+4);
  v[0]=a.x; v[1]=a.y; v[2]=a.z; v[3]=a.w; v[4]=b.x; v[5]=b.y; v[6]=b.z; v[7]=b.w;
}

template<int K, bool XG, bool XSQ>
__device__ __forceinline__ void gemm(const float* __restrict__ wt,
                                     const float* __restrict__ xg,
                                     const float* __restrict__ ACT,
                                     int tj, int tt, float (&acc)[8][8], float (&xsq)[8]){
#pragma unroll
  for(int i=0;i<8;++i)
#pragma unroll
    for(int j=0;j<8;++j) acc[i][j] = 0.f;
  const int wo = tj*8, xo = tt*8;
#pragma unroll 4
  for(int k=0;k<K;++k){
    float4 w0 = *(const float4*)(wt + k*128 + wo);
    float4 w1 = *(const float4*)(wt + k*128 + wo + 4);
    float4 xa, xb;
    if(XG){ xa = *(const float4*)(xg + k*128 + xo); xb = *(const float4*)(xg + k*128 + xo + 4); }
    else  { xa = *(const float4*)(ACT + k*ASTR + xo); xb = *(const float4*)(ACT + k*ASTR + xo + 4); }
    float xv[8] = {xa.x,xa.y,xa.z,xa.w,xb.x,xb.y,xb.z,xb.w};
    float wv[8] = {w0.x,w0.y,w0.z,w0.w,w1.x,w1.y,w1.z,w1.w};
#pragma unroll
    for(int i=0;i<8;++i){
      if(XSQ) xsq[i] = fmaf(xv[i], xv[i], xsq[i]);
#pragma unroll
      for(int j=0;j<8;++j) acc[i][j] = fmaf(xv[i], wv[j], acc[i][j]);
    }
  }
}

__device__ __forceinline__ void wACT(float* __restrict__ ACT, const float (&acc)[8][8],
                                     int tj, int tt){
#pragma unroll
  for(int j=0;j<8;++j){
    float4 a = {acc[0][j],acc[1][j],acc[2][j],acc[3][j]};
    float4 b = {acc[4][j],acc[5][j],acc[6][j],acc[7][j]};
    float* p = ACT + (tj*8+j)*ASTR + tt*8;
    *(float4*)p = a; *(float4*)(p+4) = b;
  }
}

// ---------------- main kernel: 1 block (256 thr) per batch row ---------------
// thread (tj,tt): features tj*8..+7 x tokens tt*8..+7 register tile.
__global__ __launch_bounds__(256, 2) void k_main(
    const float* __restrict__ x,
    const float* __restrict__ Wf1, const float* __restrict__ bf1,
    const float* __restrict__ Wf2, const float* __restrict__ bf2,
    const float* __restrict__ Wte, const float* __restrict__ bte,
    const float* __restrict__ Wth, const float* __restrict__ bth,
    const float* __restrict__ ws, float* __restrict__ out){
  extern __shared__ float lds[];
  float* ACT = lds + L_ACT;
  float* ZH  = lds + L_ZH;
  float* SCR = lds + L_SCR;
  float* F1V = lds + L_F1;
  const int tid = threadIdx.x, tj = tid & 15, tt = tid >> 4, b = blockIdx.x;
  const int tok0 = tt*8;
  const bool isTok = tid < 128;
  const float* xb = x + (size_t)b*4096;

  float acc[8][8];
  float xsq[8];
#pragma unroll
  for(int i=0;i<8;++i) xsq[i] = 0.f;

  // persistent per-token state (token-thread registers)
  float nf = 0.f, rr = 0.f, xnh = 1.f, thte = 0.f, thth = 0.f;

  // ================= H1: 32 -> 128(pad80), mob_relu =================
  {
    gemm<32,true,true>(ws+WTH1, xb, ACT, tj, tt, acc, xsq);
    float ebv[8]; ld8(ws+EB1+tj*8, ebv);
#pragma unroll
    for(int i=0;i<8;++i){
      float s=0.f, e=0.f;
#pragma unroll
      for(int j=0;j<8;++j){ s = fmaf(acc[i][j],acc[i][j],s); e = fmaf(acc[i][j],ebv[j],e); }
      s = rtj(s); e = rtj(e);
      if(tj==0){ SCR[tok0+i]=s; SCR[128+tok0+i]=e; SCR[256+tok0+i]=xsq[i]; }
    }
    __syncthreads();
    if(isTok){
      EX e0 = exp0(SCR[256+tid]);
      float scl0 = e0.scl;
      float m2 = SCR[tid]*scl0*scl0, meb = SCR[128+tid]*scl0;
      HS h = hyper_chain(m2, meb, e0.nh, ws[SCo+2]);
      SCR[tid] = h.ca*scl0; SCR[128+tid] = h.cb; SCR[256+tid] = lamv(h.nv);
    }
    __syncthreads();
    float cav[8],cbv[8],lmv[8];
#pragma unroll
    for(int i=0;i<8;++i){ cav[i]=SCR[tok0+i]; cbv[i]=SCR[128+tok0+i]; lmv[i]=SCR[256+tok0+i]; }
#pragma unroll
    for(int i=0;i<8;++i){
      float s=0.f;
#pragma unroll
      for(int j=0;j<8;++j){
        float v = fmaxf(lmv[i]*fmaf(cav[i],acc[i][j],cbv[i]*ebv[j]), 0.f);
        acc[i][j]=v; s = fmaf(v,v,s);
      }
      s = rtj(s);
      if(tj==0) SCR[384+tok0+i]=s;
    }
    __syncthreads();
    if(isTok){ TT tr = tail_relu(SCR[384+tid]); nf = tr.nf; SCR[384+tid]=tr.tau; }
    __syncthreads();
#pragma unroll
    for(int i=0;i<8;++i){ float tau=SCR[384+tok0+i];
#pragma unroll
      for(int j=0;j<8;++j) acc[i][j]*=tau; }
    wACT(ACT, acc, tj, tt);
    __syncthreads();
  }

  // ================= H2: 80 -> 128(pad104), mob_relu =================
  {
    gemm<80,false,false>(ws+WTH2, nullptr, ACT, tj, tt, acc, xsq);
    float ebv[8]; ld8(ws+EB2+tj*8, ebv);
#pragma unroll
    for(int i=0;i<8;++i){
      float s=0.f, e=0.f;
#pragma unroll
      for(int j=0;j<8;++j){ s = fmaf(acc[i][j],acc[i][j],s); e = fmaf(acc[i][j],ebv[j],e); }
      s = rtj(s); e = rtj(e);
      if(tj==0){ SCR[tok0+i]=s; SCR[128+tok0+i]=e; }
    }
    __syncthreads();
    if(isTok){
      HS h = hyper_chain(SCR[tid], SCR[128+tid], nf, ws[SCo+3]);
      SCR[tid]=h.ca; SCR[128+tid]=h.cb; SCR[256+tid]=lamv(h.nv);
    }
    __syncthreads();
    float cav[8],cbv[8],lmv[8];
#pragma unroll
    for(int i=0;i<8;++i){ cav[i]=SCR[tok0+i]; cbv[i]=SCR[128+tok0+i]; lmv[i]=SCR[256+tok0+i]; }
#pragma unroll
    for(int i=0;i<8;++i){
      float s=0.f;
#pragma unroll
      for(int j=0;j<8;++j){
        float v = fmaxf(lmv[i]*fmaf(cav[i],acc[i][j],cbv[i]*ebv[j]), 0.f);
        acc[i][j]=v; s = fmaf(v,v,s);
      }
      s = rtj(s);
      if(tj==0) SCR[384+tok0+i]=s;
    }
    __syncthreads();
    if(isTok){ TT tr = tail_relu(SCR[384+tid]); nf = tr.nf; SCR[384+tid]=tr.tau; }
    __syncthreads();
#pragma unroll
    for(int i=0;i<8;++i){ float tau=SCR[384+tok0+i];
#pragma unroll
      for(int j=0;j<8;++j) acc[i][j]*=tau; }
    wACT(ACT, acc, tj, tt);
    __syncthreads();
  }

  // ================= H3: 104 -> 128, p_linear only (out_h) =================
  {
    gemm<104,false,false>(ws+WTH3, nullptr, ACT, tj, tt, acc, xsq);
    float ebv[8]; ld8(ws+EB3+tj*8, ebv);
#pragma unroll
    for(int i=0;i<8;++i){
      float s=0.f, e=0.f;
#pragma unroll
      for(int j=0;j<8;++j){ s = fmaf(acc[i][j],acc[i][j],s); e = fmaf(acc[i][j],ebv[j],e); }
      s = rtj(s); e = rtj(e);
      if(tj==0){ SCR[tok0+i]=s; SCR[128+tok0+i]=e; }
    }
    __syncthreads();
    if(isTok){
      HS h = hyper_chain(SCR[tid], SCR[128+tid], nf, ws[SCo+4]);
      xnh = fmaxf(h.nv, MINN);
      rr  = art_(SQC*xnh);
      SCR[tid]=h.ca; SCR[128+tid]=h.cb;
    }
    __syncthreads();
    float cav[8],cbv[8];
#pragma unroll
    for(int i=0;i<8;++i){ cav[i]=SCR[tok0+i]; cbv[i]=SCR[128+tok0+i]; }
#pragma unroll
    for(int i=0;i<8;++i)
#pragma unroll
      for(int j=0;j<8;++j) acc[i][j] = fmaf(cav[i],acc[i][j],cbv[i]*ebv[j]);
    wACT(ACT, acc, tj, tt);
    // zh[ic][t] = Wf1[ic,128+j] . out_h  (classifier fold)
#pragma unroll
    for(int ic=0;ic<10;++ic){
      float wf[8]; ld8(Wf1 + ic*256 + 128 + tj*8, wf);
#pragma unroll
      for(int i=0;i<8;++i){
        float s=0.f;
#pragma unroll
        for(int j=0;j<8;++j) s = fmaf(acc[i][j], wf[j], s);
        s = rtj(s);
        if(tj==0) ZH[ic*128 + tok0 + i] = s;
      }
    }
    __syncthreads();
  }

  // ================= Wah pass: 4 reductions of mx = Wah . out_h =============
  {
    gemm<128,false,false>(ws+WTAH, nullptr, ACT, tj, tt, acc, xsq);
    float w1v[8], w2v[8], eav[8];
    ld8(Wte + tj*8, w1v); ld8(Wth + tj*8, w2v); ld8(ws+EBA+tj*8, eav);
#pragma unroll
    for(int i=0;i<8;++i){
      float s0=0.f,s1=0.f,s2=0.f,s3=0.f;
#pragma unroll
      for(int j=0;j<8;++j){
        float m = acc[i][j];
        s0 = fmaf(m,m,s0); s1 = fmaf(m,w1v[j],s1);
        s2 = fmaf(m,w2v[j],s2); s3 = fmaf(m,eav[j],s3);
      }
      s0=rtj(s0); s1=rtj(s1); s2=rtj(s2); s3=rtj(s3);
      if(tj==0){ SCR[tok0+i]=s0; SCR[128+tok0+i]=s1; SCR[256+tok0+i]=s2; SCR[384+tok0+i]=s3; }
    }
    __syncthreads();
    if(isTok){
      THW a = ahchain(SCR[tid], SCR[128+tid], SCR[256+tid], SCR[384+tid],
                      xnh, rr, ws[SCo+5], ws[SCo+6], ws[SCo+7]);
      thte = a.te; thth = a.th2;
    }
  }

  // ================= E1: relu(We1 x + be1) =================
  {
    gemm<32,true,false>(ws+WTE1, xb, ACT, tj, tt, acc, xsq);
    float bev[8]; ld8(ws+BE1+tj*8, bev);
#pragma unroll
    for(int i=0;i<8;++i)
#pragma unroll
      for(int j=0;j<8;++j) acc[i][j] = fmaxf(acc[i][j]+bev[j], 0.f);
    wACT(ACT, acc, tj, tt);
    __syncthreads();
  }
  // ================= E2 =================
  {
    gemm<80,false,false>(ws+WTE2, nullptr, ACT, tj, tt, acc, xsq);
    float bev[8]; ld8(ws+BE2+tj*8, bev);
#pragma unroll
    for(int i=0;i<8;++i)
#pragma unroll
      for(int j=0;j<8;++j) acc[i][j] = fmaxf(acc[i][j]+bev[j], 0.f);
    __syncthreads();            // all E2 reads of ACT done before overwrite
    wACT(ACT, acc, tj, tt);
    __syncthreads();
  }
  // ======== E3: out_e (in regs) -> d1,d2, ze; attention; classifier ========
  {
    gemm<104,false,false>(ws+WTE3, nullptr, ACT, tj, tt, acc, xsq);
    float bev[8], u1v[8], u2v[8];
    ld8(ws+BE3+tj*8, bev); ld8(ws+U1o+tj*8, u1v); ld8(ws+U2o+tj*8, u2v);
#pragma unroll
    for(int i=0;i<8;++i){
      float s1=0.f, s2=0.f;
#pragma unroll
      for(int j=0;j<8;++j){
        float v = fmaxf(acc[i][j]+bev[j], 0.f);
        acc[i][j] = v;
        s1 = fmaf(v,u1v[j],s1); s2 = fmaf(v,u2v[j],s2);
      }
      s1=rtj(s1); s2=rtj(s2);
      if(tj==0){ SCR[tok0+i]=s1; SCR[128+tok0+i]=s2; }
    }
#pragma unroll
    for(int ic=0;ic<10;++ic){
      float wf[8]; ld8(Wf1 + ic*256 + tj*8, wf);
#pragma unroll
      for(int i=0;i<8;++i){
        float s=0.f;
#pragma unroll
        for(int j=0;j<8;++j) s = fmaf(acc[i][j], wf[j], s);
        s = rtj(s);
        if(tj==0) SCR[(2+ic)*128 + tok0 + i] = s;
      }
    }
    __syncthreads();
    if(isTok){
      float d1 = SCR[tid] + ws[SCo+0];
      float d2 = SCR[128+tid] + ws[SCo+1];
      AG g = attn(d1, d2, thte, thth, rr, xnh, bte[0], bth[0]);
#pragma unroll
      for(int ic=0;ic<10;++ic){
        float p = fmaf(g.wge, SCR[(2+ic)*128+tid], g.g2 * ZH[ic*128+tid]);
        SCR[(2+ic)*128+tid] = p;
      }
    }
    __syncthreads();
    if(tid < 10){
      float s = 0.f;
      const float* P = SCR + (2+tid)*128;
      for(int t2=0;t2<128;++t2) s += P[t2];
      F1V[tid] = fmaxf(s*(1.f/128.f) + bf1[tid], 0.f);
    }
    __syncthreads();
    if(tid < 10){
      float o = bf2[tid];
#pragma unroll
      for(int k2=0;k2<10;++k2) o = fmaf(Wf2[tid*10+k2], F1V[k2], o);
      out[b*10 + tid] = o;
    }
  }
}

extern "C" void kernel_launch(void* const* d_in, const int* in_sizes, int n_in,
                              void* d_out, int out_size, void* d_ws, size_t ws_size,
                              hipStream_t stream){
  (void)in_sizes; (void)n_in; (void)out_size; (void)ws_size;
  const float* x   = (const float*)d_in[0];
  const float* We1 = (const float*)d_in[1];
  const float* be1 = (const float*)d_in[2];
  const float* We2 = (const float*)d_in[3];
  const float* be2 = (const float*)d_in[4];
  const float* We3 = (const float*)d_in[5];
  const float* be3 = (const float*)d_in[6];
  const float* Wh1 = (const float*)d_in[7];
  const float* bh1 = (const float*)d_in[8];
  const float* Wh2 = (const float*)d_in[9];
  const float* bh2 = (const float*)d_in[10];
  const float* Wh3 = (const float*)d_in[11];
  const float* bh3 = (const float*)d_in[12];
  const float* Wae = (const float*)d_in[13];
  const float* bae = (const float*)d_in[14];
  const float* Wah = (const float*)d_in[15];
  const float* bah = (const float*)d_in[16];
  const float* Wte = (const float*)d_in[17];
  const float* bte = (const float*)d_in[18];
  const float* Wth = (const float*)d_in[19];
  const float* bth = (const float*)d_in[20];
  const float* Wf1 = (const float*)d_in[21];
  const float* bf1 = (const float*)d_in[22];
  const float* Wf2 = (const float*)d_in[23];
  const float* bf2 = (const float*)d_in[24];
  float* ws  = (float*)d_ws;
  float* out = (float*)d_out;

  hipLaunchKernelGGL(k_setup_a, dim3(1), dim3(256), 0, stream,
                     Wae, bae, bh1, bh2, bh3, bah, Wte, Wth, be1, be2, be3, ws);
  hipLaunchKernelGGL(k_trans, dim3(560), dim3(128), 0, stream,
                     Wh1, Wh2, Wh3, Wah, We1, We2, We3, ws);

  const int smem = L_TOT * 4;   // 77,376 B
  hipFuncSetAttribute((const void*)k_main,
                      hipFuncAttributeMaxDynamicSharedMemorySize, smem);
  hipLaunchKernelGGL(k_main, dim3(1024), dim3(256), smem, stream,
                     x, Wf1, bf1, Wf2, bf2, Wte, bte, Wth, bth, ws, out);
}

// Round 7
// 572.471 us; speedup vs baseline: 15.7000x; 1.0846x over previous
//
#include <hip/hip_runtime.h>
#include <math.h>

constexpr float CC   = 1.2f;
constexpr float SQC  = 1.09544511501033215f;      // sqrt(1.2)
constexpr float MAXN = (1.0f - 4e-3f) / SQC;      // geoopt projx maxnorm
constexpr float MINN = 1e-15f;

// ---------------- ws float offsets (transposed padded weights + constants) ----
constexpr int WTH1 = 0;        // [32][128]
constexpr int WTH2 = 4096;     // [80][128]
constexpr int WTH3 = 14336;    // [104][128]
constexpr int WTAH = 27648;    // [128][128]
constexpr int WTE1 = 44032;    // [32][128]
constexpr int WTE2 = 48128;    // [80][128]
constexpr int WTE3 = 58368;    // [104][128]
constexpr int EB1  = 71680;    // expmap0(bh1) padded 128
constexpr int EB2  = 71808;
constexpr int EB3  = 71936;
constexpr int EBA  = 72064;
constexpr int BE1  = 72192;    // be1 padded 128
constexpr int BE2  = 72320;
constexpr int BE3  = 72448;
constexpr int U1o  = 72576;    // Wae^T wte
constexpr int U2o  = 72704;    // Wae^T wth
constexpr int SCo  = 72832;    // c1,c2,y2h1,y2h2,y2h3,y2ah,EBW1,EBW2
constexpr int PART = 72864;    // 2048 blocks x 10 classifier partials

// ---------------- LDS float offsets (64-token half-row blocks) ----------------
constexpr int ASTR  = 65;      // ACT row stride: 8*65 mod 32 = 8 -> 4-way max
constexpr int L_ACT = 0;       // 128*65 = 8320
constexpr int L_ZH  = 8320;    // 10*64
constexpr int L_SCR = 8960;    // 12*64 scratch slots
constexpr int L_TOT = 9728;    // 38,912 B -> 4 blocks/CU (16 waves/CU)

// ---------------- scalar math ----------------
__device__ __forceinline__ float art_(float x){
  x = fminf(fmaxf(x, -0.9999999f), 0.9999999f);
  return 0.5f * __logf((1.0f + x) / (1.0f - x));
}
__device__ __forceinline__ float tanh_(float x){
  x = fminf(fmaxf(x, -15.0f), 15.0f);
  float e = __expf(2.0f * x);
  return (e - 1.0f) / (e + 1.0f);
}
__device__ __forceinline__ float wsum(float v){
#pragma unroll
  for(int i=32;i>0;i>>=1) v += __shfl_xor(v, i, 64);
  return v;
}
__device__ __forceinline__ float rtj(float v){   // sum over the 16 tj lanes
  v += __shfl_xor(v, 1, 64); v += __shfl_xor(v, 2, 64);
  v += __shfl_xor(v, 4, 64); v += __shfl_xor(v, 8, 64);
  return v;
}
__device__ __forceinline__ float lamv(float nv){
  float n = fmaxf(nv, MINN);
  return art_(SQC*n)/(SQC*n);
}
struct HS { float ca, cb, nv; };
__device__ __forceinline__ HS hyper_chain(float m2, float meb, float xn_in, float y2){
  float xn  = fmaxf(xn_in, MINN);
  float mxn = fmaxf(sqrtf(m2), MINN);
  float r   = art_(SQC*xn);
  float s   = tanh_(mxn/xn*r)/(mxn*SQC);
  float nr  = s*mxn;
  if(nr > MAXN){ s *= MAXN/nr; nr = MAXN; }
  float xy = s*meb, x2 = nr*nr;
  float den = fmaxf(1.f + 2.f*CC*xy + CC*CC*x2*y2, MINN);
  float A   = (1.f + 2.f*CC*xy + CC*y2)/den;
  float Bc  = (1.f - CC*x2)/den;
  float n3  = sqrtf(fmaxf(A*A*x2 + 2.f*A*Bc*xy + Bc*Bc*y2, 0.f));
  float rho = (n3 > MAXN) ? MAXN/n3 : 1.f;
  HS h; h.nv = fminf(n3, MAXN); h.ca = rho*A*s; h.cb = rho*Bc;
  return h;
}
struct TT { float tau, nf; };
__device__ __forceinline__ TT tail_relu(float rn2){
  float rn = fmaxf(sqrtf(rn2), MINN);
  float th = tanh_(SQC*rn);
  TT r; r.tau = th/(SQC*rn); r.nf = th/SQC;
  if(r.nf > MAXN){ r.tau *= MAXN/r.nf; r.nf = MAXN; }
  return r;
}
struct EX { float nh, scl; };
__device__ __forceinline__ EX exp0(float n2){
  float n0 = fmaxf(sqrtf(n2), MINN);
  float th = tanh_(SQC*n0);
  EX e; e.nh = th/SQC; e.scl = th/(SQC*n0);
  if(e.nh > MAXN){ e.scl *= MAXN/e.nh; e.nh = MAXN; }
  return e;
}
struct THW { float te, th2; };
__device__ __forceinline__ THW ahchain(float m2a, float mw1, float mw2, float meba,
                                       float xnh, float rr, float y2,
                                       float ebw1, float ebw2){
  float mxn = fmaxf(sqrtf(m2a), MINN);
  float s = tanh_(mxn/xnh*rr)/(mxn*SQC);
  float nr = s*mxn;
  if(nr > MAXN){ s *= MAXN/nr; nr = MAXN; }
  float xy = s*meba, x2 = nr*nr;
  float den = fmaxf(1.f + 2.f*CC*xy + CC*CC*x2*y2, MINN);
  float A = (1.f + 2.f*CC*xy + CC*y2)/den;
  float Bc = (1.f - CC*x2)/den;
  float n3 = sqrtf(fmaxf(A*A*x2 + 2.f*A*Bc*xy + Bc*Bc*y2, 0.f));
  float rho = (n3 > MAXN) ? MAXN/n3 : 1.f;
  float nv = fminf(n3, MAXN);
  float lr = lamv(nv)*rho;
  THW r; r.te = lr*(A*s*mw1 + Bc*ebw1); r.th2 = lr*(A*s*mw2 + Bc*ebw2);
  return r;
}
struct AG { float wge, g2; };
__device__ __forceinline__ AG attn(float d1, float d2, float thte, float thth,
                                   float rr, float xnh, float b_e, float b_h){
  float a_e = 0.5f*(d1 - thte) + b_e;
  float a_h = 0.5f*(thth - d2) + b_h;
  float mx = fmaxf(a_e, a_h);
  float ee = __expf(a_e - mx), eh = __expf(a_h - mx);
  float inv = 1.f/(ee + eh);
  AG r; r.wge = ee*inv;
  float wgh = eh*inv;
  float inner = wgh*rr;
  float scl2 = tanh_(inner)/(xnh*SQC);
  float nn = scl2*xnh;
  if(nn > MAXN){ scl2 *= MAXN/nn; nn = MAXN; }
  r.g2 = lamv(nn)*scl2;
  return r;
}

// ---------------- setup A: folded constants ----------------
__global__ void k_setup_a(const float* __restrict__ Wae, const float* __restrict__ bae,
                          const float* __restrict__ bh1, const float* __restrict__ bh2,
                          const float* __restrict__ bh3, const float* __restrict__ bah,
                          const float* __restrict__ Wte, const float* __restrict__ Wth,
                          const float* __restrict__ be1, const float* __restrict__ be2,
                          const float* __restrict__ be3, float* __restrict__ ws){
  const int tid = threadIdx.x;            // 256 threads, 1 block
  {
    const int which = tid >> 7, k = tid & 127;
    const float* wv = which ? Wth : Wte;
    float s = 0.f;
#pragma unroll 4
    for(int j=0;j<128;++j) s += Wae[j*128+k] * wv[j];
    ws[(which ? U2o : U1o) + k] = s;
  }
  if(tid < 128){
    ws[BE1+tid] = (tid < 80)  ? be1[tid] : 0.f;
    ws[BE2+tid] = (tid < 104) ? be2[tid] : 0.f;
    ws[BE3+tid] = be3[tid];
  }
  if(tid < 64){
    const int l = tid;
    float p1=0.f, p2=0.f;
    for(int j=l;j<128;j+=64){ p1 += bae[j]*Wte[j]; p2 += bae[j]*Wth[j]; }
    p1 = wsum(p1); p2 = wsum(p2);
    if(l==0){ ws[SCo+0]=p1; ws[SCo+1]=p2; }
    const float* bs[4] = {bh1,bh2,bh3,bah};
    const int dims[4]  = {80,104,128,128};
    const int offs[4]  = {EB1,EB2,EB3,EBA};
    for(int v=0;v<4;++v){
      const float* bp = bs[v]; const int D = dims[v];
      float q = 0.f;
      for(int j=l;j<D;j+=64) q += bp[j]*bp[j];
      q = wsum(q);
      float nb = fmaxf(sqrtf(q), MINN);
      float th = tanhf(fminf(fmaxf(SQC*nb,-15.f),15.f));
      float coef = th/(SQC*nb);
      float ne = th/SQC;
      if(ne > MAXN){ coef *= MAXN/ne; ne = MAXN; }
      for(int j=l;j<D;j+=64) ws[offs[v]+j] = coef*bp[j];
      for(int j=D+l;j<128;j+=64) ws[offs[v]+j] = 0.f;   // pad
      if(l==0) ws[SCo+2+v] = ne*ne;
      if(v==3){
        float e1=0.f, e2=0.f;
        for(int j=l;j<D;j+=64){ e1 += bp[j]*Wte[j]; e2 += bp[j]*Wth[j]; }
        e1 = wsum(e1)*coef; e2 = wsum(e2)*coef;
        if(l==0){ ws[SCo+6]=e1; ws[SCo+7]=e2; }
      }
    }
  }
}

// ---------------- setup B: transpose + pad weights into ws (k-major) --------
__global__ void k_trans(const float* __restrict__ Wh1, const float* __restrict__ Wh2,
                        const float* __restrict__ Wh3, const float* __restrict__ Wah,
                        const float* __restrict__ We1, const float* __restrict__ We2,
                        const float* __restrict__ We3, float* __restrict__ ws){
  const int blk = blockIdx.x, j = threadIdx.x;   // grid 560, block 128
  const float* W; int OUT, K, kk, dst;
  if(blk < 32)       { W=Wh1; OUT=80;  K=32;  kk=blk;      dst=WTH1; }
  else if(blk < 112) { W=Wh2; OUT=104; K=80;  kk=blk-32;   dst=WTH2; }
  else if(blk < 216) { W=Wh3; OUT=128; K=104; kk=blk-112;  dst=WTH3; }
  else if(blk < 344) { W=Wah; OUT=128; K=128; kk=blk-216;  dst=WTAH; }
  else if(blk < 376) { W=We1; OUT=80;  K=32;  kk=blk-344;  dst=WTE1; }
  else if(blk < 456) { W=We2; OUT=104; K=80;  kk=blk-376;  dst=WTE2; }
  else               { W=We3; OUT=128; K=104; kk=blk-456;  dst=WTE3; }
  ws[dst + kk*128 + j] = (j < OUT) ? W[j*K + kk] : 0.f;
}

// ---------------- finishing kernel: combine halves + classifier ----------------
__global__ void k_fin(const float* __restrict__ ws, const float* __restrict__ bf1,
                      const float* __restrict__ Wf2, const float* __restrict__ bf2,
                      float* __restrict__ out){
  const int r = blockIdx.x*64 + threadIdx.x;   // grid 16 x 64 = 1024 rows
  const float* p = ws + PART + (size_t)r*20;
  float f1[10];
#pragma unroll
  for(int i=0;i<10;++i)
    f1[i] = fmaxf((p[i] + p[10+i])*(1.f/128.f) + bf1[i], 0.f);
#pragma unroll
  for(int o=0;o<10;++o){
    float a = bf2[o];
#pragma unroll
    for(int k=0;k<10;++k) a = fmaf(Wf2[o*10+k], f1[k], a);
    out[r*10 + o] = a;
  }
}

// ---------------- GEMM inner: 8 feat x 4 tok register tile per thread --------
__device__ __forceinline__ void ld8(const float* __restrict__ p, float (&v)[8]){
  float4 a = *(const float4*)p, b = *(const float4*)(p+4);
  v[0]=a.x; v[1]=a.y; v[2]=a.z; v[3]=a.w; v[4]=b.x; v[5]=b.y; v[6]=b.z; v[7]=b.w;
}

template<int K, bool XG, bool XSQ>
__device__ __forceinline__ void gemm4(const float* __restrict__ wt,
                                      const float* __restrict__ xg,
                                      const float* __restrict__ ACT,
                                      int tj, int tt, float (&acc)[4][8], float (&xsq)[4]){
#pragma unroll
  for(int i=0;i<4;++i)
#pragma unroll
    for(int j=0;j<8;++j) acc[i][j] = 0.f;
  const int wo = tj*8, xo = tt*4;
#pragma unroll 4
  for(int k=0;k<K;++k){
    float4 w0 = *(const float4*)(wt + k*128 + wo);
    float4 w1 = *(const float4*)(wt + k*128 + wo + 4);
    float4 xa;
    if(XG) xa = *(const float4*)(xg + k*128 + xo);
    else   xa = *(const float4*)(ACT + k*ASTR + xo);
    float xv[4] = {xa.x,xa.y,xa.z,xa.w};
    float wv[8] = {w0.x,w0.y,w0.z,w0.w,w1.x,w1.y,w1.z,w1.w};
#pragma unroll
    for(int i=0;i<4;++i){
      if(XSQ) xsq[i] = fmaf(xv[i], xv[i], xsq[i]);
#pragma unroll
      for(int j=0;j<8;++j) acc[i][j] = fmaf(xv[i], wv[j], acc[i][j]);
    }
  }
}

__device__ __forceinline__ void wACT(float* __restrict__ ACT, const float (&acc)[4][8],
                                     int tj, int tt){
#pragma unroll
  for(int j=0;j<8;++j){
    float4 a = {acc[0][j],acc[1][j],acc[2][j],acc[3][j]};
    *(float4*)(ACT + (tj*8+j)*ASTR + tt*4) = a;
  }
}

// ---------------- main kernel: 1 block (256 thr) per 64-token half-row --------
// thread (tj,tt): features tj*8..+7 x tokens tt*4..+3 register tile.
__global__ __launch_bounds__(256, 4) void k_main(
    const float* __restrict__ x,
    const float* __restrict__ Wf1, const float* __restrict__ Wte,
    const float* __restrict__ bte, const float* __restrict__ Wth,
    const float* __restrict__ bth, float* __restrict__ ws){
  extern __shared__ float lds[];
  float* ACT = lds + L_ACT;
  float* ZH  = lds + L_ZH;
  float* SCR = lds + L_SCR;
  const int tid = threadIdx.x, tj = tid & 15, tt = tid >> 4;
  const int b = blockIdx.x, b2 = b >> 1, hf = b & 1;
  const int tok0 = tt*4;
  const bool isTok = tid < 64;
  const float* xg = x + (size_t)b2*4096 + hf*64;

  float acc[4][8];
  float xsq[4];
#pragma unroll
  for(int i=0;i<4;++i) xsq[i] = 0.f;

  // persistent per-token state (token-thread registers, tid<64)
  float nf = 0.f, rr = 0.f, xnh = 1.f, thte = 0.f, thth = 0.f;

  // ================= H1: 32 -> 128(pad80), mob_relu =================
  {
    gemm4<32,true,true>(ws+WTH1, xg, ACT, tj, tt, acc, xsq);
    float ebv[8]; ld8(ws+EB1+tj*8, ebv);
#pragma unroll
    for(int i=0;i<4;++i){
      float s=0.f, e=0.f;
#pragma unroll
      for(int j=0;j<8;++j){ s = fmaf(acc[i][j],acc[i][j],s); e = fmaf(acc[i][j],ebv[j],e); }
      s = rtj(s); e = rtj(e);
      if(tj==0){ SCR[tok0+i]=s; SCR[64+tok0+i]=e; SCR[128+tok0+i]=xsq[i]; }
    }
    __syncthreads();
    if(isTok){
      EX e0 = exp0(SCR[128+tid]);
      float scl0 = e0.scl;
      float m2 = SCR[tid]*scl0*scl0, meb = SCR[64+tid]*scl0;
      HS h = hyper_chain(m2, meb, e0.nh, ws[SCo+2]);
      SCR[tid] = h.ca*scl0; SCR[64+tid] = h.cb; SCR[128+tid] = lamv(h.nv);
    }
    __syncthreads();
    float cav[4],cbv[4],lmv[4];
#pragma unroll
    for(int i=0;i<4;++i){ cav[i]=SCR[tok0+i]; cbv[i]=SCR[64+tok0+i]; lmv[i]=SCR[128+tok0+i]; }
#pragma unroll
    for(int i=0;i<4;++i){
      float s=0.f;
#pragma unroll
      for(int j=0;j<8;++j){
        float v = fmaxf(lmv[i]*fmaf(cav[i],acc[i][j],cbv[i]*ebv[j]), 0.f);
        acc[i][j]=v; s = fmaf(v,v,s);
      }
      s = rtj(s);
      if(tj==0) SCR[192+tok0+i]=s;
    }
    __syncthreads();
    if(isTok){ TT tr = tail_relu(SCR[192+tid]); nf = tr.nf; SCR[192+tid]=tr.tau; }
    __syncthreads();
#pragma unroll
    for(int i=0;i<4;++i){ float tau=SCR[192+tok0+i];
#pragma unroll
      for(int j=0;j<8;++j) acc[i][j]*=tau; }
    wACT(ACT, acc, tj, tt);
    __syncthreads();
  }

  // ================= H2: 80 -> 128(pad104), mob_relu =================
  {
    gemm4<80,false,false>(ws+WTH2, nullptr, ACT, tj, tt, acc, xsq);
    float ebv[8]; ld8(ws+EB2+tj*8, ebv);
#pragma unroll
    for(int i=0;i<4;++i){
      float s=0.f, e=0.f;
#pragma unroll
      for(int j=0;j<8;++j){ s = fmaf(acc[i][j],acc[i][j],s); e = fmaf(acc[i][j],ebv[j],e); }
      s = rtj(s); e = rtj(e);
      if(tj==0){ SCR[tok0+i]=s; SCR[64+tok0+i]=e; }
    }
    __syncthreads();
    if(isTok){
      HS h = hyper_chain(SCR[tid], SCR[64+tid], nf, ws[SCo+3]);
      SCR[tid]=h.ca; SCR[64+tid]=h.cb; SCR[128+tid]=lamv(h.nv);
    }
    __syncthreads();
    float cav[4],cbv[4],lmv[4];
#pragma unroll
    for(int i=0;i<4;++i){ cav[i]=SCR[tok0+i]; cbv[i]=SCR[64+tok0+i]; lmv[i]=SCR[128+tok0+i]; }
#pragma unroll
    for(int i=0;i<4;++i){
      float s=0.f;
#pragma unroll
      for(int j=0;j<8;++j){
        float v = fmaxf(lmv[i]*fmaf(cav[i],acc[i][j],cbv[i]*ebv[j]), 0.f);
        acc[i][j]=v; s = fmaf(v,v,s);
      }
      s = rtj(s);
      if(tj==0) SCR[192+tok0+i]=s;
    }
    __syncthreads();
    if(isTok){ TT tr = tail_relu(SCR[192+tid]); nf = tr.nf; SCR[192+tid]=tr.tau; }
    __syncthreads();
#pragma unroll
    for(int i=0;i<4;++i){ float tau=SCR[192+tok0+i];
#pragma unroll
      for(int j=0;j<8;++j) acc[i][j]*=tau; }
    wACT(ACT, acc, tj, tt);
    __syncthreads();
  }

  // ================= H3: 104 -> 128, p_linear only (out_h) =================
  {
    gemm4<104,false,false>(ws+WTH3, nullptr, ACT, tj, tt, acc, xsq);
    float ebv[8]; ld8(ws+EB3+tj*8, ebv);
#pragma unroll
    for(int i=0;i<4;++i){
      float s=0.f, e=0.f;
#pragma unroll
      for(int j=0;j<8;++j){ s = fmaf(acc[i][j],acc[i][j],s); e = fmaf(acc[i][j],ebv[j],e); }
      s = rtj(s); e = rtj(e);
      if(tj==0){ SCR[tok0+i]=s; SCR[64+tok0+i]=e; }
    }
    __syncthreads();
    if(isTok){
      HS h = hyper_chain(SCR[tid], SCR[64+tid], nf, ws[SCo+4]);
      xnh = fmaxf(h.nv, MINN);
      rr  = art_(SQC*xnh);
      SCR[tid]=h.ca; SCR[64+tid]=h.cb;
    }
    __syncthreads();
    float cav[4],cbv[4];
#pragma unroll
    for(int i=0;i<4;++i){ cav[i]=SCR[tok0+i]; cbv[i]=SCR[64+tok0+i]; }
#pragma unroll
    for(int i=0;i<4;++i)
#pragma unroll
      for(int j=0;j<8;++j) acc[i][j] = fmaf(cav[i],acc[i][j],cbv[i]*ebv[j]);
    wACT(ACT, acc, tj, tt);
    // zh[ic][t] = Wf1[ic,128+j] . out_h  (classifier fold)
#pragma unroll
    for(int ic=0;ic<10;++ic){
      float wf[8]; ld8(Wf1 + ic*256 + 128 + tj*8, wf);
#pragma unroll
      for(int i=0;i<4;++i){
        float s=0.f;
#pragma unroll
        for(int j=0;j<8;++j) s = fmaf(acc[i][j], wf[j], s);
        s = rtj(s);
        if(tj==0) ZH[ic*64 + tok0 + i] = s;
      }
    }
    __syncthreads();
  }

  // ================= Wah pass: 4 reductions of mx = Wah . out_h =============
  {
    gemm4<128,false,false>(ws+WTAH, nullptr, ACT, tj, tt, acc, xsq);
    float w1v[8], w2v[8], eav[8];
    ld8(Wte + tj*8, w1v); ld8(Wth + tj*8, w2v); ld8(ws+EBA+tj*8, eav);
#pragma unroll
    for(int i=0;i<4;++i){
      float s0=0.f,s1=0.f,s2=0.f,s3=0.f;
#pragma unroll
      for(int j=0;j<8;++j){
        float m = acc[i][j];
        s0 = fmaf(m,m,s0); s1 = fmaf(m,w1v[j],s1);
        s2 = fmaf(m,w2v[j],s2); s3 = fmaf(m,eav[j],s3);
      }
      s0=rtj(s0); s1=rtj(s1); s2=rtj(s2); s3=rtj(s3);
      if(tj==0){ SCR[tok0+i]=s0; SCR[64+tok0+i]=s1; SCR[128+tok0+i]=s2; SCR[192+tok0+i]=s3; }
    }
    __syncthreads();
    if(isTok){
      THW a = ahchain(SCR[tid], SCR[64+tid], SCR[128+tid], SCR[192+tid],
                      xnh, rr, ws[SCo+5], ws[SCo+6], ws[SCo+7]);
      thte = a.te; thth = a.th2;
    }
  }

  // ================= E1: relu(We1 x + be1) =================
  {
    gemm4<32,true,false>(ws+WTE1, xg, ACT, tj, tt, acc, xsq);
    float bev[8]; ld8(ws+BE1+tj*8, bev);
#pragma unroll
    for(int i=0;i<4;++i)
#pragma unroll
      for(int j=0;j<8;++j) acc[i][j] = fmaxf(acc[i][j]+bev[j], 0.f);
    __syncthreads();            // Wah gemm reads of ACT all done (barrier above covers), keep for safety
    wACT(ACT, acc, tj, tt);
    __syncthreads();
  }
  // ================= E2 =================
  {
    gemm4<80,false,false>(ws+WTE2, nullptr, ACT, tj, tt, acc, xsq);
    float bev[8]; ld8(ws+BE2+tj*8, bev);
#pragma unroll
    for(int i=0;i<4;++i)
#pragma unroll
      for(int j=0;j<8;++j) acc[i][j] = fmaxf(acc[i][j]+bev[j], 0.f);
    __syncthreads();            // all E2 reads of ACT done before overwrite
    wACT(ACT, acc, tj, tt);
    __syncthreads();
  }
  // ======== E3: out_e (in regs) -> d1,d2, ze; attention; partials ========
  {
    gemm4<104,false,false>(ws+WTE3, nullptr, ACT, tj, tt, acc, xsq);
    float bev[8], u1v[8], u2v[8];
    ld8(ws+BE3+tj*8, bev); ld8(ws+U1o+tj*8, u1v); ld8(ws+U2o+tj*8, u2v);
#pragma unroll
    for(int i=0;i<4;++i){
      float s1=0.f, s2=0.f;
#pragma unroll
      for(int j=0;j<8;++j){
        float v = fmaxf(acc[i][j]+bev[j], 0.f);
        acc[i][j] = v;
        s1 = fmaf(v,u1v[j],s1); s2 = fmaf(v,u2v[j],s2);
      }
      s1=rtj(s1); s2=rtj(s2);
      if(tj==0){ SCR[tok0+i]=s1; SCR[64+tok0+i]=s2; }
    }
#pragma unroll
    for(int ic=0;ic<10;++ic){
      float wf[8]; ld8(Wf1 + ic*256 + tj*8, wf);
#pragma unroll
      for(int i=0;i<4;++i){
        float s=0.f;
#pragma unroll
        for(int j=0;j<8;++j) s = fmaf(acc[i][j], wf[j], s);
        s = rtj(s);
        if(tj==0) SCR[(2+ic)*64 + tok0 + i] = s;
      }
    }
    __syncthreads();
    if(isTok){
      float d1 = SCR[tid] + ws[SCo+0];
      float d2 = SCR[64+tid] + ws[SCo+1];
      AG g = attn(d1, d2, thte, thth, rr, xnh, bte[0], bth[0]);
      float pv[10];
#pragma unroll
      for(int ic=0;ic<10;++ic){
        float p = fmaf(g.wge, SCR[(2+ic)*64+tid], g.g2 * ZH[ic*64+tid]);
        pv[ic] = wsum(p);           // sum over this block's 64 tokens
      }
      if(tid == 0){
#pragma unroll
        for(int ic=0;ic<10;++ic) ws[PART + (size_t)b*10 + ic] = pv[ic];
      }
    }
  }
}

extern "C" void kernel_launch(void* const* d_in, const int* in_sizes, int n_in,
                              void* d_out, int out_size, void* d_ws, size_t ws_size,
                              hipStream_t stream){
  (void)in_sizes; (void)n_in; (void)out_size; (void)ws_size;
  const float* x   = (const float*)d_in[0];
  const float* We1 = (const float*)d_in[1];
  const float* be1 = (const float*)d_in[2];
  const float* We2 = (const float*)d_in[3];
  const float* be2 = (const float*)d_in[4];
  const float* We3 = (const float*)d_in[5];
  const float* be3 = (const float*)d_in[6];
  const float* Wh1 = (const float*)d_in[7];
  const float* bh1 = (const float*)d_in[8];
  const float* Wh2 = (const float*)d_in[9];
  const float* bh2 = (const float*)d_in[10];
  const float* Wh3 = (const float*)d_in[11];
  const float* bh3 = (const float*)d_in[12];
  const float* Wae = (const float*)d_in[13];
  const float* bae = (const float*)d_in[14];
  const float* Wah = (const float*)d_in[15];
  const float* bah = (const float*)d_in[16];
  const float* Wte = (const float*)d_in[17];
  const float* bte = (const float*)d_in[18];
  const float* Wth = (const float*)d_in[19];
  const float* bth = (const float*)d_in[20];
  const float* Wf1 = (const float*)d_in[21];
  const float* bf1 = (const float*)d_in[22];
  const float* Wf2 = (const float*)d_in[23];
  const float* bf2 = (const float*)d_in[24];
  float* ws  = (float*)d_ws;
  float* out = (float*)d_out;

  hipLaunchKernelGGL(k_setup_a, dim3(1), dim3(256), 0, stream,
                     Wae, bae, bh1, bh2, bh3, bah, Wte, Wth, be1, be2, be3, ws);
  hipLaunchKernelGGL(k_trans, dim3(560), dim3(128), 0, stream,
                     Wh1, Wh2, Wh3, Wah, We1, We2, We3, ws);

  const int smem = L_TOT * 4;   // 38,912 B -> 4 blocks/CU
  hipLaunchKernelGGL(k_main, dim3(2048), dim3(256), smem, stream,
                     x, Wf1, Wte, bte, Wth, bth, ws);

  hipLaunchKernelGGL(k_fin, dim3(16), dim3(64), 0, stream,
                     ws, bf1, Wf2, bf2, out);
}